// Round 3
// baseline (953.819 us; speedup 1.0000x reference)
//
#include <hip/hip_runtime.h>
#include <math.h>

// Problem constants
#define Bq 2
#define Nn 20000
#define Ee 20000
#define Aa 8
#define Hh 256
#define TEe 32
constexpr int BE   = Bq * Ee;    // 40000
constexpr int BN   = Bq * Nn;    // 40000
constexpr int KTE  = 9;          // enc K-tiles (288/32)
constexpr int KTU  = 16;         // upd K-tiles (512/32)
constexpr int LDAE = 296;        // padded enc A row (ushorts): 288+8
constexpr int LDAU = 520;        // padded upd A row (ushorts): 512+8
constexpr int SLCAP = 1024;

typedef __attribute__((ext_vector_type(8))) short bf16x8;
typedef __attribute__((ext_vector_type(4))) float f32x4;
typedef unsigned short u16;
typedef unsigned int   u32;

__device__ __forceinline__ u16 f2bf(float f) {           // RNE f32 -> bf16
    u32 u = __float_as_uint(f);
    u32 r = u + 0x7FFFu + ((u >> 16) & 1u);
    return (u16)(r >> 16);
}
__device__ __forceinline__ float bf2f(u16 h) {
    return __uint_as_float(((u32)h) << 16);
}
__device__ __forceinline__ float gelu_f(float x) {
    return 0.5f * x * (1.f + erff(x * 0.70710678118654752440f));
}
__device__ __forceinline__ f32x4 mfma16(bf16x8 a, bf16x8 b, f32x4 c) {
    return __builtin_amdgcn_mfma_f32_16x16x32_bf16(a, b, c, 0, 0, 0);
}

// mask dtype sniffing: bit1 => f32 mask, bit0 => u8 mask, none => i32
__device__ __forceinline__ float mask_at(const void* mp, int flag, int i) {
    if (flag & 2) return ((const float*)mp)[i];
    if (flag & 1) return ((const unsigned char*)mp)[i] ? 1.f : 0.f;
    return ((const int*)mp)[i] ? 1.f : 0.f;
}

__global__ void k_zero(float4* p, int n4) {
    int i = blockIdx.x * blockDim.x + threadIdx.x;
    int stride = gridDim.x * blockDim.x;
    float4 z; z.x = 0.f; z.y = 0.f; z.z = 0.f; z.w = 0.f;
    for (; i < n4; i += stride) p[i] = z;
}

__global__ void k_detect(const unsigned int* mw, int n, int* flag) {
    int found = 0;
    for (int i = blockIdx.x * blockDim.x + threadIdx.x; i < n;
         i += gridDim.x * blockDim.x) {
        unsigned int w = mw[i];
        if (w == 0x3F800000u) found |= 2;
        else if (w > 1u) found |= 1;
    }
    __shared__ int sf;
    if (threadIdx.x == 0) sf = 0;
    __syncthreads();
    if (found) atomicOr(&sf, found);
    __syncthreads();
    if (threadIdx.x == 0 && sf) atomicOr(flag, sf);
}

// convert f32 -> bf16, 4 at a time
__global__ void k_cvt(const float4* __restrict__ in, ushort4* __restrict__ o, int n4) {
    for (int i = blockIdx.x * blockDim.x + threadIdx.x; i < n4;
         i += gridDim.x * blockDim.x) {
        float4 v = in[i];
        ushort4 u; u.x = f2bf(v.x); u.y = f2bf(v.y); u.z = f2bf(v.z); u.w = f2bf(v.w);
        o[i] = u;
    }
}

// pack W [K][256] f32 into MFMA B-fragment order:
// Wp[((nt*KT+kt)*64 + lane)*8 + j] = bf16(W[kt*32+(lane>>4)*8+j][nt*16+(lane&15)])
__global__ void k_pack(const float* __restrict__ W, u16* __restrict__ Wp,
                       int KT, int nthreads) {
    int t = blockIdx.x * blockDim.x + threadIdx.x;
    if (t >= nthreads) return;
    int lane = t & 63, tile = t >> 6;
    int kt = tile % KT, nt = tile / KT;
    int kbase = kt * 32 + (lane >> 4) * 8;
    int col = nt * 16 + (lane & 15);
    u16 tmp[8];
    #pragma unroll
    for (int j = 0; j < 8; j++) tmp[j] = f2bf(W[(size_t)(kbase + j) * Hh + col]);
    *(uint4*)(Wp + (size_t)t * 8) = *(const uint4*)tmp;
}

__global__ void k_count(const int* __restrict__ members, const void* __restrict__ maskp,
                        const int* __restrict__ flagp, int* __restrict__ deg) {
    int flag = flagp[0];
    for (int i = blockIdx.x * blockDim.x + threadIdx.x; i < BE * Aa;
         i += gridDim.x * blockDim.x) {
        if (mask_at(maskp, flag, i) != 0.f) {
            int ge = i >> 3;
            int b = ge / Ee;
            int idx = min(max(members[i], 0), Nn - 1);
            atomicAdd(&deg[b * Nn + idx], 1);
        }
    }
}

__global__ __launch_bounds__(1024) void k_scan(const int* __restrict__ deg,
                                               int* __restrict__ offs,
                                               int* __restrict__ cur) {
    __shared__ int part[1024];
    const int T = 1024, C = (BN + T - 1) / T;
    int t = threadIdx.x, base = t * C, s = 0;
    for (int i = 0; i < C; i++) { int j = base + i; if (j < BN) s += deg[j]; }
    part[t] = s;
    __syncthreads();
    for (int d = 1; d < T; d <<= 1) {
        int v = (t >= d) ? part[t - d] : 0;
        __syncthreads();
        part[t] += v;
        __syncthreads();
    }
    int run = (t > 0) ? part[t - 1] : 0;
    for (int i = 0; i < C; i++) {
        int j = base + i;
        if (j < BN) { offs[j] = run; cur[j] = run; run += deg[j]; }
    }
    if (t == T - 1) offs[BN] = part[T - 1];
}

__global__ void k_fill(const int* __restrict__ members, const void* __restrict__ maskp,
                       const int* __restrict__ flagp, int* __restrict__ cur,
                       int* __restrict__ list) {
    int flag = flagp[0];
    for (int i = blockIdx.x * blockDim.x + threadIdx.x; i < BE * Aa;
         i += gridDim.x * blockDim.x) {
        if (mask_at(maskp, flag, i) != 0.f) {
            int ge = i >> 3;
            int b = ge / Ee;
            int idx = min(max(members[i], 0), Nn - 1);
            int pos = atomicAdd(&cur[b * Nn + idx], 1);
            list[pos] = ge;
        }
    }
}

// ---------------- Edge phase (MFMA) ----------------
// 64 edges/block, 256 threads = 4 waves; wave w owns cols [w*64, w*64+64).
template <bool NFBF>
__global__ __launch_bounds__(256) void k_edge(
    const float* __restrict__ nf, const u16* __restrict__ nfb,
    const int* __restrict__ members, const int* __restrict__ types,
    const void* __restrict__ maskp, const float* __restrict__ ett,
    const bf16x8* __restrict__ Wp, const float* __restrict__ benc,
    const float* __restrict__ genc, const float* __restrict__ beenc,
    const int* __restrict__ flagp, uint4* __restrict__ ef4) {
    __shared__ __align__(16) u16 s_a[64][LDAE];   // 37.9 KB
    __shared__ float s_red[64][4], s_red2[64][4];
    __shared__ float s_stats[64][2];
    __shared__ int   s_idx[64][Aa];
    __shared__ float s_m[64][Aa];
    __shared__ float s_cnt[64];
    __shared__ int   s_type[64];

    const int tid = threadIdx.x;
    const int e0  = blockIdx.x * 64;
    const int flag = flagp[0];

    for (int i = tid; i < 64 * Aa; i += 256) {
        int gi = e0 * Aa + i;
        int e = i >> 3;
        int b = (e0 + e) / Ee;
        int idx = min(max(members[gi], 0), Nn - 1);
        s_idx[e][i & 7] = b * Nn + idx;   // global node row
        s_m[e][i & 7] = mask_at(maskp, flag, gi);
    }
    if (tid < 64) s_type[tid] = types[e0 + tid];
    __syncthreads();
    if (tid < 64) {
        float c = 0.f;
        #pragma unroll
        for (int a = 0; a < Aa; a++) c += s_m[tid][a];
        s_cnt[tid] = fmaxf(c, 1.f);
    }
    __syncthreads();

    // pooling: thread = column
    {
        const int c = tid;
        for (int e = 0; e < 64; e++) {
            float acc = 0.f;
            #pragma unroll
            for (int a = 0; a < Aa; a++) {
                float m = s_m[e][a];
                if (m != 0.f) {
                    float v = NFBF ? bf2f(nfb[(size_t)s_idx[e][a] * Hh + c])
                                   : nf[(size_t)s_idx[e][a] * Hh + c];
                    acc = fmaf(m, v, acc);
                }
            }
            s_a[e][c] = f2bf(acc / s_cnt[e]);
        }
        int ec = tid >> 5, cc = tid & 31;
        #pragma unroll
        for (int ii = 0; ii < 8; ii++) {
            int e = ii * 8 + ec;
            s_a[e][Hh + cc] = f2bf(ett[s_type[e] * TEe + cc]);
        }
    }
    __syncthreads();

    const int w = tid >> 6, lane = tid & 63;
    const int l15 = lane & 15, lg = lane >> 4;

    f32x4 acc[4][4];
    #pragma unroll
    for (int m = 0; m < 4; m++)
        #pragma unroll
        for (int n = 0; n < 4; n++) acc[m][n] = (f32x4){0.f, 0.f, 0.f, 0.f};

    for (int kt = 0; kt < KTE; kt++) {
        bf16x8 bfr[4], afr[4];
        #pragma unroll
        for (int n = 0; n < 4; n++)
            bfr[n] = Wp[((size_t)((w * 4 + n) * KTE + kt)) * 64 + lane];
        #pragma unroll
        for (int m = 0; m < 4; m++)
            afr[m] = *(const bf16x8*)&s_a[m * 16 + l15][kt * 32 + lg * 8];
        #pragma unroll
        for (int m = 0; m < 4; m++)
            #pragma unroll
            for (int n = 0; n < 4; n++)
                acc[m][n] = mfma16(afr[m], bfr[n], acc[m][n]);
    }

    // bias + gelu, then LN over the 256 cols
    float bia[4], gam[4], bet[4];
    #pragma unroll
    for (int n = 0; n < 4; n++) bia[n] = benc[w * 64 + n * 16 + l15];
    #pragma unroll
    for (int m = 0; m < 4; m++)
        #pragma unroll
        for (int n = 0; n < 4; n++)
            #pragma unroll
            for (int j = 0; j < 4; j++)
                acc[m][n][j] = gelu_f(acc[m][n][j] + bia[n]);

    #pragma unroll
    for (int m = 0; m < 4; m++)
        #pragma unroll
        for (int j = 0; j < 4; j++) {
            float s = 0.f, s2 = 0.f;
            #pragma unroll
            for (int n = 0; n < 4; n++) {
                float v = acc[m][n][j];
                s += v; s2 = fmaf(v, v, s2);
            }
            #pragma unroll
            for (int mk = 1; mk < 16; mk <<= 1) {
                s  += __shfl_xor(s, mk, 64);
                s2 += __shfl_xor(s2, mk, 64);
            }
            if (l15 == 0) {
                int r = m * 16 + lg * 4 + j;
                s_red[r][w] = s; s_red2[r][w] = s2;
            }
        }
    __syncthreads();
    if (tid < 64) {
        float s  = s_red[tid][0] + s_red[tid][1] + s_red[tid][2] + s_red[tid][3];
        float s2 = s_red2[tid][0] + s_red2[tid][1] + s_red2[tid][2] + s_red2[tid][3];
        float mu = s * (1.f / Hh);
        float var = s2 * (1.f / Hh) - mu * mu;
        s_stats[tid][0] = mu;
        s_stats[tid][1] = rsqrtf(var + 1e-5f);
    }
    __syncthreads();
    #pragma unroll
    for (int n = 0; n < 4; n++) {
        int col = w * 64 + n * 16 + l15;
        gam[n] = genc[col]; bet[n] = beenc[col];
    }
    #pragma unroll
    for (int m = 0; m < 4; m++)
        #pragma unroll
        for (int j = 0; j < 4; j++) {
            int r = m * 16 + lg * 4 + j;
            float mu = s_stats[r][0], rs = s_stats[r][1];
            #pragma unroll
            for (int n = 0; n < 4; n++) {
                float val = (acc[m][n][j] - mu) * rs * gam[n] + bet[n];
                s_a[r][w * 64 + n * 16 + l15] = f2bf(val);
            }
        }
    __syncthreads();

    // coalesced 16B stores of the bf16 edge features
    const uint4* sa4 = (const uint4*)&s_a[0][0];   // row stride = 37 uint4
    #pragma unroll
    for (int i = 0; i < 8; i++) {
        int idx = i * 256 + tid;
        int r = idx >> 5, cc = idx & 31;
        ef4[(size_t)(e0 + r) * 32 + cc] = sa4[r * 37 + cc];
    }
}

// ---------------- Node phase (MFMA) ----------------
template <bool NFBF>
__global__ __launch_bounds__(256) void k_node(
    const float* __restrict__ nf, const u16* __restrict__ nfb,
    const u16* __restrict__ efb, const int* __restrict__ offs,
    const int* __restrict__ list, const bf16x8* __restrict__ Wp,
    const float* __restrict__ bupd, const float* __restrict__ gupd,
    const float* __restrict__ beupd, float* __restrict__ out) {
    __shared__ __align__(16) u16 s_a[64][LDAU];   // 66.6 KB
    __shared__ float s_red[64][4], s_red2[64][4];
    __shared__ float s_stats[64][2];
    __shared__ int   s_offs[65];
    __shared__ int   s_list[SLCAP];

    const int tid = threadIdx.x;
    const int n0  = blockIdx.x * 64;

    if (tid < 65) s_offs[tid] = offs[n0 + tid];
    __syncthreads();
    const int segbase = s_offs[0];
    const int segtot  = s_offs[64] - segbase;
    const bool staged = segtot <= SLCAP;
    if (staged)
        for (int j = tid; j < segtot; j += 256) s_list[j] = list[segbase + j];

    // stage nf half of A (cols 0..255)
    if (NFBF) {
        uint4* saw = (uint4*)&s_a[0][0];           // row stride 65 uint4
        const uint4* nf4 = (const uint4*)nfb + (size_t)n0 * 32;
        #pragma unroll
        for (int i = 0; i < 8; i++) {
            int idx = i * 256 + tid;
            int r = idx >> 5, cc = idx & 31;
            saw[r * 65 + cc] = nf4[r * 32 + cc];
        }
    } else {
        const float4* nf4 = (const float4*)nf + (size_t)n0 * 64;
        #pragma unroll
        for (int i = 0; i < 16; i++) {
            int idx = i * 256 + tid;
            int r = idx >> 6, c4 = idx & 63;
            float4 v = nf4[r * 64 + c4];
            ushort4 u; u.x = f2bf(v.x); u.y = f2bf(v.y); u.z = f2bf(v.z); u.w = f2bf(v.w);
            *(ushort4*)&s_a[r][c4 * 4] = u;
        }
    }
    __syncthreads();   // s_list + nf staging complete

    // gather upd half (cols 256..511): thread = column
    {
        const int c = tid;
        for (int i = 0; i < 64; i++) {
            int o0 = s_offs[i] - segbase;
            int d  = s_offs[i + 1] - s_offs[i];
            float acc = 0.f;
            for (int j = 0; j < d; j++) {
                int ge = staged ? s_list[o0 + j] : list[segbase + o0 + j];
                acc += bf2f(efb[(size_t)ge * Hh + c]);
            }
            s_a[i][Hh + c] = f2bf(acc / fmaxf((float)d, 1.f));
        }
    }
    __syncthreads();

    const int w = tid >> 6, lane = tid & 63;
    const int l15 = lane & 15, lg = lane >> 4;

    f32x4 acc[4][4];
    #pragma unroll
    for (int m = 0; m < 4; m++)
        #pragma unroll
        for (int n = 0; n < 4; n++) acc[m][n] = (f32x4){0.f, 0.f, 0.f, 0.f};

    for (int kt = 0; kt < KTU; kt++) {
        bf16x8 bfr[4], afr[4];
        #pragma unroll
        for (int n = 0; n < 4; n++)
            bfr[n] = Wp[((size_t)((w * 4 + n) * KTU + kt)) * 64 + lane];
        #pragma unroll
        for (int m = 0; m < 4; m++)
            afr[m] = *(const bf16x8*)&s_a[m * 16 + l15][kt * 32 + lg * 8];
        #pragma unroll
        for (int m = 0; m < 4; m++)
            #pragma unroll
            for (int n = 0; n < 4; n++)
                acc[m][n] = mfma16(afr[m], bfr[n], acc[m][n]);
    }

    float bia[4], gam[4], bet[4];
    #pragma unroll
    for (int n = 0; n < 4; n++) bia[n] = bupd[w * 64 + n * 16 + l15];
    #pragma unroll
    for (int m = 0; m < 4; m++)
        #pragma unroll
        for (int n = 0; n < 4; n++)
            #pragma unroll
            for (int j = 0; j < 4; j++)
                acc[m][n][j] = gelu_f(acc[m][n][j] + bia[n]);

    #pragma unroll
    for (int m = 0; m < 4; m++)
        #pragma unroll
        for (int j = 0; j < 4; j++) {
            float s = 0.f, s2 = 0.f;
            #pragma unroll
            for (int n = 0; n < 4; n++) {
                float v = acc[m][n][j];
                s += v; s2 = fmaf(v, v, s2);
            }
            #pragma unroll
            for (int mk = 1; mk < 16; mk <<= 1) {
                s  += __shfl_xor(s, mk, 64);
                s2 += __shfl_xor(s2, mk, 64);
            }
            if (l15 == 0) {
                int r = m * 16 + lg * 4 + j;
                s_red[r][w] = s; s_red2[r][w] = s2;
            }
        }
    __syncthreads();
    if (tid < 64) {
        float s  = s_red[tid][0] + s_red[tid][1] + s_red[tid][2] + s_red[tid][3];
        float s2 = s_red2[tid][0] + s_red2[tid][1] + s_red2[tid][2] + s_red2[tid][3];
        float mu = s * (1.f / Hh);
        float var = s2 * (1.f / Hh) - mu * mu;
        s_stats[tid][0] = mu;
        s_stats[tid][1] = rsqrtf(var + 1e-5f);
    }
    __syncthreads();
    #pragma unroll
    for (int n = 0; n < 4; n++) {
        int col = w * 64 + n * 16 + l15;
        gam[n] = gupd[col]; bet[n] = beupd[col];
    }
    // write f32 results into LDS (reuse s_a as float, row stride 260)
    float* s_f = (float*)&s_a[0][0];
    #pragma unroll
    for (int m = 0; m < 4; m++)
        #pragma unroll
        for (int j = 0; j < 4; j++) {
            int r = m * 16 + lg * 4 + j;
            float mu = s_stats[r][0], rs = s_stats[r][1];
            #pragma unroll
            for (int n = 0; n < 4; n++) {
                float val = (acc[m][n][j] - mu) * rs * gam[n] + bet[n];
                s_f[r * 260 + w * 64 + n * 16 + l15] = val;
            }
        }
    __syncthreads();
    const float4* sf4 = (const float4*)s_f;        // row stride 65 float4
    float4* out4 = (float4*)out + (size_t)n0 * 64;
    #pragma unroll
    for (int i = 0; i < 16; i++) {
        int idx = i * 256 + tid;
        int r = idx >> 6, c4 = idx & 63;
        out4[r * 64 + c4] = sf4[r * 65 + c4];
    }
}

extern "C" void kernel_launch(void* const* d_in, const int* in_sizes, int n_in,
                              void* d_out, int out_size, void* d_ws, size_t ws_size,
                              hipStream_t stream) {
    const float* nf    = (const float*)d_in[0];
    const int* members = (const int*)d_in[1];
    const int* types   = (const int*)d_in[2];
    const void* maskp  = d_in[3];
    const float* ett   = (const float*)d_in[4];
    const float* Wenc  = (const float*)d_in[5];
    const float* benc  = (const float*)d_in[6];
    const float* genc  = (const float*)d_in[7];
    const float* beenc = (const float*)d_in[8];
    const float* Wupd  = (const float*)d_in[9];
    const float* bupd  = (const float*)d_in[10];
    const float* gupd  = (const float*)d_in[11];
    const float* beupd = (const float*)d_in[12];
    float* out = (float*)d_out;

    // workspace layout
    int* ip   = (int*)d_ws;
    int* flag = ip;                       // 64 ints
    int* deg  = ip + 64;                  // BN
    int* offs = deg + BN;                 // BN+16
    int* cur  = offs + BN + 16;           // BN
    int* list = cur + BN;                 // BE*Aa
    char* p   = (char*)(list + BE * Aa);
    u16* efb    = (u16*)p;                p += (size_t)BE * Hh * 2;  // 20.48 MB
    u16* WencP  = (u16*)p;                p += (size_t)16 * KTE * 64 * 8 * 2;
    u16* WupdP  = (u16*)p;                p += (size_t)16 * KTU * 64 * 8 * 2;
    u16* nfb    = (u16*)p;                p += (size_t)BN * Hh * 2;  // 20.48 MB
    const bool use_nfbf = ((size_t)(p - (char*)d_ws) <= ws_size);

    int n4 = (64 + BN) / 4;
    hipLaunchKernelGGL(k_zero, dim3(64), dim3(256), 0, stream, (float4*)ip, n4);
    hipLaunchKernelGGL(k_detect, dim3(256), dim3(256), 0, stream,
                       (const unsigned int*)maskp, BE * Aa / 4, flag);
    if (use_nfbf)
        hipLaunchKernelGGL(k_cvt, dim3(2048), dim3(256), 0, stream,
                           (const float4*)nf, (ushort4*)nfb, BN * Hh / 4);
    hipLaunchKernelGGL(k_pack, dim3(36), dim3(256), 0, stream,
                       Wenc, WencP, KTE, 16 * KTE * 64);
    hipLaunchKernelGGL(k_pack, dim3(64), dim3(256), 0, stream,
                       Wupd, WupdP, KTU, 16 * KTU * 64);
    hipLaunchKernelGGL(k_count, dim3(640), dim3(256), 0, stream,
                       members, maskp, flag, deg);
    hipLaunchKernelGGL(k_scan, dim3(1), dim3(1024), 0, stream, deg, offs, cur);
    hipLaunchKernelGGL(k_fill, dim3(640), dim3(256), 0, stream,
                       members, maskp, flag, cur, list);
    if (use_nfbf) {
        hipLaunchKernelGGL((k_edge<true>), dim3(BE / 64), dim3(256), 0, stream,
                           nf, nfb, members, types, maskp, ett,
                           (const bf16x8*)WencP, benc, genc, beenc, flag,
                           (uint4*)efb);
        hipLaunchKernelGGL((k_node<true>), dim3(BN / 64), dim3(256), 0, stream,
                           nf, nfb, efb, offs, list, (const bf16x8*)WupdP,
                           bupd, gupd, beupd, out);
    } else {
        hipLaunchKernelGGL((k_edge<false>), dim3(BE / 64), dim3(256), 0, stream,
                           nf, nfb, members, types, maskp, ett,
                           (const bf16x8*)WencP, benc, genc, beenc, flag,
                           (uint4*)efb);
        hipLaunchKernelGGL((k_node<false>), dim3(BN / 64), dim3(256), 0, stream,
                           nf, nfb, efb, offs, list, (const bf16x8*)WupdP,
                           bupd, gupd, beupd, out);
    }
}

// Round 4
// 277.877 us; speedup vs baseline: 3.4325x; 3.4325x over previous
//
#include <hip/hip_runtime.h>
#include <math.h>

// Problem constants
#define Bq 2
#define Nn 20000
#define Ee 20000
#define Aa 8
#define Hh 256
#define TEe 32
constexpr int BE   = Bq * Ee;    // 40000
constexpr int BN   = Bq * Nn;    // 40000
constexpr int KTE  = 9;          // enc K-tiles (288/32)
constexpr int KTU  = 16;         // upd K-tiles (512/32)
constexpr int LDAE = 296;        // padded enc A row (ushorts)
constexpr int LDAU = 520;        // padded upd A row (ushorts)
constexpr int EPB  = 32;         // edges per block
constexpr int NPB  = 32;         // nodes per block
constexpr int SLCAP = 2048;

typedef __attribute__((ext_vector_type(8))) short bf16x8;
typedef __attribute__((ext_vector_type(4))) float f32x4;
typedef unsigned short u16;
typedef unsigned int   u32;

__device__ __forceinline__ u16 f2bf(float f) {           // RNE f32 -> bf16
    u32 u = __float_as_uint(f);
    u32 r = u + 0x7FFFu + ((u >> 16) & 1u);
    return (u16)(r >> 16);
}
__device__ __forceinline__ float bf2f(u16 h) {
    return __uint_as_float(((u32)h) << 16);
}
__device__ __forceinline__ float gelu_f(float x) {
    return 0.5f * x * (1.f + erff(x * 0.70710678118654752440f));
}
__device__ __forceinline__ f32x4 mfma16(bf16x8 a, bf16x8 b, f32x4 c) {
    return __builtin_amdgcn_mfma_f32_16x16x32_bf16(a, b, c, 0, 0, 0);
}

// mask dtype sniffing: bit1 => f32 mask, bit0 => u8 mask, none => i32
__device__ __forceinline__ float mask_at(const void* mp, int flag, int i) {
    if (flag & 2) return ((const float*)mp)[i];
    if (flag & 1) return ((const unsigned char*)mp)[i] ? 1.f : 0.f;
    return ((const int*)mp)[i] ? 1.f : 0.f;
}

__global__ void k_zero(float4* p, int n4) {
    int i = blockIdx.x * blockDim.x + threadIdx.x;
    int stride = gridDim.x * blockDim.x;
    float4 z; z.x = 0.f; z.y = 0.f; z.z = 0.f; z.w = 0.f;
    for (; i < n4; i += stride) p[i] = z;
}

__global__ void k_detect(const unsigned int* mw, int n, int* flag) {
    int found = 0;
    for (int i = blockIdx.x * blockDim.x + threadIdx.x; i < n;
         i += gridDim.x * blockDim.x) {
        unsigned int w = mw[i];
        if (w == 0x3F800000u) found |= 2;
        else if (w > 1u) found |= 1;
    }
    __shared__ int sf;
    if (threadIdx.x == 0) sf = 0;
    __syncthreads();
    if (found) atomicOr(&sf, found);
    __syncthreads();
    if (threadIdx.x == 0 && sf) atomicOr(flag, sf);
}

__global__ void k_cvt(const float4* __restrict__ in, ushort4* __restrict__ o, int n4) {
    for (int i = blockIdx.x * blockDim.x + threadIdx.x; i < n4;
         i += gridDim.x * blockDim.x) {
        float4 v = in[i];
        ushort4 u; u.x = f2bf(v.x); u.y = f2bf(v.y); u.z = f2bf(v.z); u.w = f2bf(v.w);
        o[i] = u;
    }
}

// pack W [K][256] f32 into MFMA B-fragment order
__global__ void k_pack(const float* __restrict__ W, u16* __restrict__ Wp,
                       int KT, int nthreads) {
    int t = blockIdx.x * blockDim.x + threadIdx.x;
    if (t >= nthreads) return;
    int lane = t & 63, tile = t >> 6;
    int kt = tile % KT, nt = tile / KT;
    int kbase = kt * 32 + (lane >> 4) * 8;
    int col = nt * 16 + (lane & 15);
    u16 tmp[8];
    #pragma unroll
    for (int j = 0; j < 8; j++) tmp[j] = f2bf(W[(size_t)(kbase + j) * Hh + col]);
    *(uint4*)(Wp + (size_t)t * 8) = *(const uint4*)tmp;
}

__global__ void k_count(const int* __restrict__ members, const void* __restrict__ maskp,
                        const int* __restrict__ flagp, int* __restrict__ deg) {
    int flag = flagp[0];
    for (int i = blockIdx.x * blockDim.x + threadIdx.x; i < BE * Aa;
         i += gridDim.x * blockDim.x) {
        if (mask_at(maskp, flag, i) != 0.f) {
            int ge = i >> 3;
            int b = ge / Ee;
            int idx = min(max(members[i], 0), Nn - 1);
            atomicAdd(&deg[b * Nn + idx], 1);
        }
    }
}

__global__ __launch_bounds__(1024) void k_scan(const int* __restrict__ deg,
                                               int* __restrict__ offs,
                                               int* __restrict__ cur) {
    __shared__ int part[1024];
    const int T = 1024, C = (BN + T - 1) / T;
    int t = threadIdx.x, base = t * C, s = 0;
    for (int i = 0; i < C; i++) { int j = base + i; if (j < BN) s += deg[j]; }
    part[t] = s;
    __syncthreads();
    for (int d = 1; d < T; d <<= 1) {
        int v = (t >= d) ? part[t - d] : 0;
        __syncthreads();
        part[t] += v;
        __syncthreads();
    }
    int run = (t > 0) ? part[t - 1] : 0;
    for (int i = 0; i < C; i++) {
        int j = base + i;
        if (j < BN) { offs[j] = run; cur[j] = run; run += deg[j]; }
    }
    if (t == T - 1) offs[BN] = part[T - 1];
}

__global__ void k_fill(const int* __restrict__ members, const void* __restrict__ maskp,
                       const int* __restrict__ flagp, int* __restrict__ cur,
                       int* __restrict__ list) {
    int flag = flagp[0];
    for (int i = blockIdx.x * blockDim.x + threadIdx.x; i < BE * Aa;
         i += gridDim.x * blockDim.x) {
        if (mask_at(maskp, flag, i) != 0.f) {
            int ge = i >> 3;
            int b = ge / Ee;
            int idx = min(max(members[i], 0), Nn - 1);
            int pos = atomicAdd(&cur[b * Nn + idx], 1);
            list[pos] = ge;
        }
    }
}

// ---------------- Edge phase (MFMA) ----------------
// EPB=32 edges/block, 256 threads = 4 waves; wave w owns cols [w*64, w*64+64).
template <bool NFBF>
__global__ __launch_bounds__(256) void k_edge(
    const float* __restrict__ nf, const u16* __restrict__ nfb,
    const int* __restrict__ members, const int* __restrict__ types,
    const void* __restrict__ maskp, const float* __restrict__ ett,
    const bf16x8* __restrict__ Wp, const float* __restrict__ benc,
    const float* __restrict__ genc, const float* __restrict__ beenc,
    const int* __restrict__ flagp, uint4* __restrict__ ef4) {
    __shared__ __align__(16) u16 s_a[EPB][LDAE];   // 18.9 KB
    __shared__ float s_red[EPB][4], s_red2[EPB][4];
    __shared__ float s_stats[EPB][2];
    __shared__ int   s_idx[EPB][Aa];
    __shared__ float s_m[EPB][Aa];
    __shared__ float s_rcnt[EPB];
    __shared__ int   s_type[EPB];

    const int tid = threadIdx.x;
    const int e0  = blockIdx.x * EPB;
    const int flag = flagp[0];
    const int w = tid >> 6, lane = tid & 63;

    {   // one (e,a) pair per thread
        int gi = e0 * Aa + tid;
        int e = tid >> 3;
        int b = (e0 + e) / Ee;
        int idx = min(max(members[gi], 0), Nn - 1);
        s_idx[e][tid & 7] = b * Nn + idx;
        s_m[e][tid & 7] = mask_at(maskp, flag, gi);
    }
    if (tid < EPB) s_type[tid] = types[e0 + tid];
    __syncthreads();
    if (tid < EPB) {
        float c = 0.f;
        #pragma unroll
        for (int a = 0; a < Aa; a++) c += s_m[tid][a];
        s_rcnt[tid] = 1.f / fmaxf(c, 1.f);
    }
    __syncthreads();

    // pooling: wave w handles 8 edges, lane owns 4 columns (8B loads, MLP=8)
    {
        const int c4 = lane * 4;
        #pragma unroll
        for (int ee = 0; ee < EPB / 4; ee++) {
            int e = w * (EPB / 4) + ee;
            float a0 = 0.f, a1 = 0.f, a2 = 0.f, a3 = 0.f;
            if (NFBF) {
                ushort4 v[Aa];
                #pragma unroll
                for (int a = 0; a < Aa; a++)
                    v[a] = *(const ushort4*)(nfb + (size_t)s_idx[e][a] * Hh + c4);
                #pragma unroll
                for (int a = 0; a < Aa; a++) {
                    float mm = s_m[e][a];
                    a0 = fmaf(mm, bf2f(v[a].x), a0);
                    a1 = fmaf(mm, bf2f(v[a].y), a1);
                    a2 = fmaf(mm, bf2f(v[a].z), a2);
                    a3 = fmaf(mm, bf2f(v[a].w), a3);
                }
            } else {
                float4 v[Aa];
                #pragma unroll
                for (int a = 0; a < Aa; a++)
                    v[a] = *(const float4*)(nf + (size_t)s_idx[e][a] * Hh + c4);
                #pragma unroll
                for (int a = 0; a < Aa; a++) {
                    float mm = s_m[e][a];
                    a0 = fmaf(mm, v[a].x, a0);
                    a1 = fmaf(mm, v[a].y, a1);
                    a2 = fmaf(mm, v[a].z, a2);
                    a3 = fmaf(mm, v[a].w, a3);
                }
            }
            float rc = s_rcnt[e];
            ushort4 o;
            o.x = f2bf(a0 * rc); o.y = f2bf(a1 * rc);
            o.z = f2bf(a2 * rc); o.w = f2bf(a3 * rc);
            *(ushort4*)&s_a[e][c4] = o;
        }
        // type embedding cols 256..287
        #pragma unroll
        for (int i = tid; i < EPB * TEe; i += 256) {
            int e = i >> 5, cc = i & 31;
            s_a[e][Hh + cc] = f2bf(ett[s_type[e] * TEe + cc]);
        }
    }
    __syncthreads();

    const int l15 = lane & 15, lg = lane >> 4;

    f32x4 acc[2][4];
    #pragma unroll
    for (int m = 0; m < 2; m++)
        #pragma unroll
        for (int n = 0; n < 4; n++) acc[m][n] = (f32x4){0.f, 0.f, 0.f, 0.f};

    for (int kt = 0; kt < KTE; kt++) {
        bf16x8 bfr[4], afr[2];
        #pragma unroll
        for (int n = 0; n < 4; n++)
            bfr[n] = Wp[((size_t)((w * 4 + n) * KTE + kt)) * 64 + lane];
        #pragma unroll
        for (int m = 0; m < 2; m++)
            afr[m] = *(const bf16x8*)&s_a[m * 16 + l15][kt * 32 + lg * 8];
        #pragma unroll
        for (int m = 0; m < 2; m++)
            #pragma unroll
            for (int n = 0; n < 4; n++)
                acc[m][n] = mfma16(afr[m], bfr[n], acc[m][n]);
    }

    float bia[4], gam[4], bet[4];
    #pragma unroll
    for (int n = 0; n < 4; n++) bia[n] = benc[w * 64 + n * 16 + l15];
    #pragma unroll
    for (int m = 0; m < 2; m++)
        #pragma unroll
        for (int n = 0; n < 4; n++)
            #pragma unroll
            for (int j = 0; j < 4; j++)
                acc[m][n][j] = gelu_f(acc[m][n][j] + bia[n]);

    #pragma unroll
    for (int m = 0; m < 2; m++)
        #pragma unroll
        for (int j = 0; j < 4; j++) {
            float s = 0.f, s2 = 0.f;
            #pragma unroll
            for (int n = 0; n < 4; n++) {
                float v = acc[m][n][j];
                s += v; s2 = fmaf(v, v, s2);
            }
            #pragma unroll
            for (int mk = 1; mk < 16; mk <<= 1) {
                s  += __shfl_xor(s, mk, 64);
                s2 += __shfl_xor(s2, mk, 64);
            }
            if (l15 == 0) {
                int r = m * 16 + lg * 4 + j;
                s_red[r][w] = s; s_red2[r][w] = s2;
            }
        }
    __syncthreads();
    if (tid < EPB) {
        float s  = s_red[tid][0] + s_red[tid][1] + s_red[tid][2] + s_red[tid][3];
        float s2 = s_red2[tid][0] + s_red2[tid][1] + s_red2[tid][2] + s_red2[tid][3];
        float mu = s * (1.f / Hh);
        float var = s2 * (1.f / Hh) - mu * mu;
        s_stats[tid][0] = mu;
        s_stats[tid][1] = rsqrtf(var + 1e-5f);
    }
    __syncthreads();
    #pragma unroll
    for (int n = 0; n < 4; n++) {
        int col = w * 64 + n * 16 + l15;
        gam[n] = genc[col]; bet[n] = beenc[col];
    }
    #pragma unroll
    for (int m = 0; m < 2; m++)
        #pragma unroll
        for (int j = 0; j < 4; j++) {
            int r = m * 16 + lg * 4 + j;
            float mu = s_stats[r][0], rs = s_stats[r][1];
            #pragma unroll
            for (int n = 0; n < 4; n++) {
                float val = (acc[m][n][j] - mu) * rs * gam[n] + bet[n];
                s_a[r][w * 64 + n * 16 + l15] = f2bf(val);
            }
        }
    __syncthreads();

    const uint4* sa4 = (const uint4*)&s_a[0][0];   // row stride 37 uint4
    #pragma unroll
    for (int i = 0; i < 4; i++) {
        int idx = i * 256 + tid;
        int r = idx >> 5, cc = idx & 31;
        ef4[(size_t)(e0 + r) * 32 + cc] = sa4[r * 37 + cc];
    }
}

// ---------------- Node phase (MFMA) ----------------
template <bool NFBF>
__global__ __launch_bounds__(256) void k_node(
    const float* __restrict__ nf, const u16* __restrict__ nfb,
    const u16* __restrict__ efb, const int* __restrict__ offs,
    const int* __restrict__ list, const bf16x8* __restrict__ Wp,
    const float* __restrict__ bupd, const float* __restrict__ gupd,
    const float* __restrict__ beupd, float* __restrict__ out) {
    __shared__ __align__(16) u16 s_a[NPB][LDAU];   // 33.3 KB
    __shared__ float s_red[NPB][4], s_red2[NPB][4];
    __shared__ float s_stats[NPB][2];
    __shared__ int   s_offs[NPB + 1];
    __shared__ int   s_list[SLCAP + 8];

    const int tid = threadIdx.x;
    const int n0  = blockIdx.x * NPB;
    const int w = tid >> 6, lane = tid & 63;

    if (tid < NPB + 1) s_offs[tid] = offs[n0 + tid];
    __syncthreads();
    const int segbase = s_offs[0];
    const int segtot  = s_offs[NPB] - segbase;
    const bool staged = segtot <= SLCAP;
    if (staged)
        for (int j = tid; j < segtot; j += 256) s_list[j] = list[segbase + j];

    // stage nf half of A (cols 0..255)
    if (NFBF) {
        uint4* saw = (uint4*)&s_a[0][0];           // row stride 65 uint4
        const uint4* nf4 = (const uint4*)nfb + (size_t)n0 * 32;
        #pragma unroll
        for (int i = 0; i < 4; i++) {
            int idx = i * 256 + tid;
            int r = idx >> 5, cc = idx & 31;
            saw[r * 65 + cc] = nf4[r * 32 + cc];
        }
    } else {
        const float4* nf4 = (const float4*)nf + (size_t)n0 * 64;
        #pragma unroll
        for (int i = 0; i < 8; i++) {
            int idx = i * 256 + tid;
            int r = idx >> 6, c4 = idx & 63;
            float4 v = nf4[r * 64 + c4];
            ushort4 u; u.x = f2bf(v.x); u.y = f2bf(v.y); u.z = f2bf(v.z); u.w = f2bf(v.w);
            *(ushort4*)&s_a[r][c4 * 4] = u;
        }
    }
    __syncthreads();   // s_list + nf staging complete

    // gather upd half (cols 256..511): wave w handles 8 nodes, lane owns 4 cols
    {
        const int c4 = lane * 4;
        #pragma unroll
        for (int ii = 0; ii < NPB / 4; ii++) {
            int i = w * (NPB / 4) + ii;
            int o0 = s_offs[i] - segbase;
            int d  = s_offs[i + 1] - s_offs[i];
            float a0 = 0.f, a1 = 0.f, a2 = 0.f, a3 = 0.f;
            for (int j0 = 0; j0 < d; j0 += 8) {
                ushort4 v[8];
                #pragma unroll
                for (int q = 0; q < 8; q++) {
                    int j = j0 + q;
                    int ge;
                    if (staged) ge = (j < d) ? s_list[o0 + j] : BE;
                    else        ge = (j < d) ? list[segbase + o0 + j] : BE;
                    v[q] = *(const ushort4*)(efb + (size_t)ge * Hh + c4);
                }
                #pragma unroll
                for (int q = 0; q < 8; q++) {
                    a0 += bf2f(v[q].x); a1 += bf2f(v[q].y);
                    a2 += bf2f(v[q].z); a3 += bf2f(v[q].w);
                }
            }
            float rc = 1.f / fmaxf((float)d, 1.f);
            ushort4 o;
            o.x = f2bf(a0 * rc); o.y = f2bf(a1 * rc);
            o.z = f2bf(a2 * rc); o.w = f2bf(a3 * rc);
            *(ushort4*)&s_a[i][Hh + c4] = o;
        }
    }
    __syncthreads();

    const int l15 = lane & 15, lg = lane >> 4;

    f32x4 acc[2][4];
    #pragma unroll
    for (int m = 0; m < 2; m++)
        #pragma unroll
        for (int n = 0; n < 4; n++) acc[m][n] = (f32x4){0.f, 0.f, 0.f, 0.f};

    for (int kt = 0; kt < KTU; kt++) {
        bf16x8 bfr[4], afr[2];
        #pragma unroll
        for (int n = 0; n < 4; n++)
            bfr[n] = Wp[((size_t)((w * 4 + n) * KTU + kt)) * 64 + lane];
        #pragma unroll
        for (int m = 0; m < 2; m++)
            afr[m] = *(const bf16x8*)&s_a[m * 16 + l15][kt * 32 + lg * 8];
        #pragma unroll
        for (int m = 0; m < 2; m++)
            #pragma unroll
            for (int n = 0; n < 4; n++)
                acc[m][n] = mfma16(afr[m], bfr[n], acc[m][n]);
    }

    float bia[4], gam[4], bet[4];
    #pragma unroll
    for (int n = 0; n < 4; n++) bia[n] = bupd[w * 64 + n * 16 + l15];
    #pragma unroll
    for (int m = 0; m < 2; m++)
        #pragma unroll
        for (int n = 0; n < 4; n++)
            #pragma unroll
            for (int j = 0; j < 4; j++)
                acc[m][n][j] = gelu_f(acc[m][n][j] + bia[n]);

    #pragma unroll
    for (int m = 0; m < 2; m++)
        #pragma unroll
        for (int j = 0; j < 4; j++) {
            float s = 0.f, s2 = 0.f;
            #pragma unroll
            for (int n = 0; n < 4; n++) {
                float v = acc[m][n][j];
                s += v; s2 = fmaf(v, v, s2);
            }
            #pragma unroll
            for (int mk = 1; mk < 16; mk <<= 1) {
                s  += __shfl_xor(s, mk, 64);
                s2 += __shfl_xor(s2, mk, 64);
            }
            if (l15 == 0) {
                int r = m * 16 + lg * 4 + j;
                s_red[r][w] = s; s_red2[r][w] = s2;
            }
        }
    __syncthreads();
    if (tid < NPB) {
        float s  = s_red[tid][0] + s_red[tid][1] + s_red[tid][2] + s_red[tid][3];
        float s2 = s_red2[tid][0] + s_red2[tid][1] + s_red2[tid][2] + s_red2[tid][3];
        float mu = s * (1.f / Hh);
        float var = s2 * (1.f / Hh) - mu * mu;
        s_stats[tid][0] = mu;
        s_stats[tid][1] = rsqrtf(var + 1e-5f);
    }
    __syncthreads();
    #pragma unroll
    for (int n = 0; n < 4; n++) {
        int col = w * 64 + n * 16 + l15;
        gam[n] = gupd[col]; bet[n] = beupd[col];
    }
    float* s_f = (float*)&s_a[0][0];   // reuse as f32, row stride 260
    #pragma unroll
    for (int m = 0; m < 2; m++)
        #pragma unroll
        for (int j = 0; j < 4; j++) {
            int r = m * 16 + lg * 4 + j;
            float mu = s_stats[r][0], rs = s_stats[r][1];
            #pragma unroll
            for (int n = 0; n < 4; n++) {
                float val = (acc[m][n][j] - mu) * rs * gam[n] + bet[n];
                s_f[r * 260 + w * 64 + n * 16 + l15] = val;
            }
        }
    __syncthreads();
    const float4* sf4 = (const float4*)s_f;        // row stride 65 float4
    float4* out4 = (float4*)out + (size_t)n0 * 64;
    #pragma unroll
    for (int i = 0; i < 8; i++) {
        int idx = i * 256 + tid;
        int r = idx >> 6, c4 = idx & 63;
        out4[r * 64 + c4] = sf4[r * 65 + c4];
    }
}

extern "C" void kernel_launch(void* const* d_in, const int* in_sizes, int n_in,
                              void* d_out, int out_size, void* d_ws, size_t ws_size,
                              hipStream_t stream) {
    const float* nf    = (const float*)d_in[0];
    const int* members = (const int*)d_in[1];
    const int* types   = (const int*)d_in[2];
    const void* maskp  = d_in[3];
    const float* ett   = (const float*)d_in[4];
    const float* Wenc  = (const float*)d_in[5];
    const float* benc  = (const float*)d_in[6];
    const float* genc  = (const float*)d_in[7];
    const float* beenc = (const float*)d_in[8];
    const float* Wupd  = (const float*)d_in[9];
    const float* bupd  = (const float*)d_in[10];
    const float* gupd  = (const float*)d_in[11];
    const float* beupd = (const float*)d_in[12];
    float* out = (float*)d_out;

    // workspace layout
    int* ip   = (int*)d_ws;
    int* flag = ip;                       // 64 ints
    int* deg  = ip + 64;                  // BN
    int* offs = deg + BN;                 // BN+16
    int* cur  = offs + BN + 16;           // BN
    int* list = cur + BN;                 // BE*Aa + 16
    char* p   = (char*)(list + BE * Aa + 16);
    u16* efb    = (u16*)p;                p += (size_t)(BE + 1) * Hh * 2;  // +zero row
    u16* WencP  = (u16*)p;                p += (size_t)16 * KTE * 64 * 8 * 2;
    u16* WupdP  = (u16*)p;                p += (size_t)16 * KTU * 64 * 8 * 2;
    u16* nfb    = (u16*)p;                p += (size_t)BN * Hh * 2;
    const bool use_nfbf = ((size_t)(p - (char*)d_ws) <= ws_size);

    int n4 = (64 + BN) / 4;
    hipLaunchKernelGGL(k_zero, dim3(64), dim3(256), 0, stream, (float4*)ip, n4);
    // zero the dummy efb row (row BE)
    hipLaunchKernelGGL(k_zero, dim3(1), dim3(64), 0, stream,
                       (float4*)(efb + (size_t)BE * Hh), Hh * 2 / 16);
    hipLaunchKernelGGL(k_detect, dim3(256), dim3(256), 0, stream,
                       (const unsigned int*)maskp, BE * Aa / 4, flag);
    if (use_nfbf)
        hipLaunchKernelGGL(k_cvt, dim3(2048), dim3(256), 0, stream,
                           (const float4*)nf, (ushort4*)nfb, BN * Hh / 4);
    hipLaunchKernelGGL(k_pack, dim3(36), dim3(256), 0, stream,
                       Wenc, WencP, KTE, 16 * KTE * 64);
    hipLaunchKernelGGL(k_pack, dim3(64), dim3(256), 0, stream,
                       Wupd, WupdP, KTU, 16 * KTU * 64);
    hipLaunchKernelGGL(k_count, dim3(640), dim3(256), 0, stream,
                       members, maskp, flag, deg);
    hipLaunchKernelGGL(k_scan, dim3(1), dim3(1024), 0, stream, deg, offs, cur);
    hipLaunchKernelGGL(k_fill, dim3(640), dim3(256), 0, stream,
                       members, maskp, flag, cur, list);
    if (use_nfbf) {
        hipLaunchKernelGGL((k_edge<true>), dim3(BE / EPB), dim3(256), 0, stream,
                           nf, nfb, members, types, maskp, ett,
                           (const bf16x8*)WencP, benc, genc, beenc, flag,
                           (uint4*)efb);
        hipLaunchKernelGGL((k_node<true>), dim3(BN / NPB), dim3(256), 0, stream,
                           nf, nfb, efb, offs, list, (const bf16x8*)WupdP,
                           bupd, gupd, beupd, out);
    } else {
        hipLaunchKernelGGL((k_edge<false>), dim3(BE / EPB), dim3(256), 0, stream,
                           nf, nfb, members, types, maskp, ett,
                           (const bf16x8*)WencP, benc, genc, beenc, flag,
                           (uint4*)efb);
        hipLaunchKernelGGL((k_node<false>), dim3(BN / NPB), dim3(256), 0, stream,
                           nf, nfb, efb, offs, list, (const bf16x8*)WupdP,
                           bupd, gupd, beupd, out);
    }
}

// Round 5
// 186.877 us; speedup vs baseline: 5.1040x; 1.4870x over previous
//
#include <hip/hip_runtime.h>
#include <math.h>

// Problem constants
#define Bq 2
#define Nn 20000
#define Ee 20000
#define Aa 8
#define Hh 256
#define TEe 32
constexpr int BE   = Bq * Ee;    // 40000
constexpr int BN   = Bq * Nn;    // 40000
constexpr int KTE  = 9;          // enc K-tiles (288/32)
constexpr int KTU  = 16;         // upd K-tiles (512/32)
constexpr int LDAE = 296;        // padded enc A row (ushorts)
constexpr int LDAU = 520;        // padded upd A row (ushorts)
constexpr int EPB  = 32;         // edges per block
constexpr int NPB  = 32;         // nodes per block
constexpr int SLCAP = 2048;
constexpr int SCB  = 1024;       // scan block size
constexpr int NSB  = (BN + SCB - 1) / SCB;   // 40 scan blocks

typedef __attribute__((ext_vector_type(8))) short bf16x8;
typedef __attribute__((ext_vector_type(4))) float f32x4;
typedef unsigned short u16;
typedef unsigned int   u32;

__device__ __forceinline__ u16 f2bf(float f) {           // RNE f32 -> bf16
    u32 u = __float_as_uint(f);
    u32 r = u + 0x7FFFu + ((u >> 16) & 1u);
    return (u16)(r >> 16);
}
__device__ __forceinline__ float bf2f(u16 h) {
    return __uint_as_float(((u32)h) << 16);
}
__device__ __forceinline__ float gelu_f(float x) {
    return 0.5f * x * (1.f + erff(x * 0.70710678118654752440f));
}
__device__ __forceinline__ f32x4 mfma16(bf16x8 a, bf16x8 b, f32x4 c) {
    return __builtin_amdgcn_mfma_f32_16x16x32_bf16(a, b, c, 0, 0, 0);
}

// mask dtype sniffing: bit1 => f32 mask, bit0 => u8 mask, none => i32
__device__ __forceinline__ float mask_at(const void* mp, int flag, int i) {
    if (flag & 2) return ((const float*)mp)[i];
    if (flag & 1) return ((const unsigned char*)mp)[i] ? 1.f : 0.f;
    return ((const int*)mp)[i] ? 1.f : 0.f;
}

__global__ void k_zero(float4* p, int n4) {
    int i = blockIdx.x * blockDim.x + threadIdx.x;
    int stride = gridDim.x * blockDim.x;
    float4 z; z.x = 0.f; z.y = 0.f; z.z = 0.f; z.w = 0.f;
    for (; i < n4; i += stride) p[i] = z;
}

__global__ void k_detect(const unsigned int* mw, int n, int* flag) {
    int found = 0;
    for (int i = blockIdx.x * blockDim.x + threadIdx.x; i < n;
         i += gridDim.x * blockDim.x) {
        unsigned int w = mw[i];
        if (w == 0x3F800000u) found |= 2;
        else if (w > 1u) found |= 1;
    }
    __shared__ int sf;
    if (threadIdx.x == 0) sf = 0;
    __syncthreads();
    if (found) atomicOr(&sf, found);
    __syncthreads();
    if (threadIdx.x == 0 && sf) atomicOr(flag, sf);
}

__global__ void k_cvt(const float4* __restrict__ in, ushort4* __restrict__ o, int n4) {
    for (int i = blockIdx.x * blockDim.x + threadIdx.x; i < n4;
         i += gridDim.x * blockDim.x) {
        float4 v = in[i];
        ushort4 u; u.x = f2bf(v.x); u.y = f2bf(v.y); u.z = f2bf(v.z); u.w = f2bf(v.w);
        o[i] = u;
    }
}

// pack W [K][256] f32 into MFMA B-fragment order
__global__ void k_pack(const float* __restrict__ W, u16* __restrict__ Wp,
                       int KT, int nthreads) {
    int t = blockIdx.x * blockDim.x + threadIdx.x;
    if (t >= nthreads) return;
    int lane = t & 63, tile = t >> 6;
    int kt = tile % KT, nt = tile / KT;
    int kbase = kt * 32 + (lane >> 4) * 8;
    int col = nt * 16 + (lane & 15);
    u16 tmp[8];
    #pragma unroll
    for (int j = 0; j < 8; j++) tmp[j] = f2bf(W[(size_t)(kbase + j) * Hh + col]);
    *(uint4*)(Wp + (size_t)t * 8) = *(const uint4*)tmp;
}

__global__ void k_count(const int* __restrict__ members, const void* __restrict__ maskp,
                        const int* __restrict__ flagp, int* __restrict__ deg) {
    int flag = flagp[0];
    for (int i = blockIdx.x * blockDim.x + threadIdx.x; i < BE * Aa;
         i += gridDim.x * blockDim.x) {
        if (mask_at(maskp, flag, i) != 0.f) {
            int ge = i >> 3;
            int b = ge / Ee;
            int idx = min(max(members[i], 0), Nn - 1);
            atomicAdd(&deg[b * Nn + idx], 1);
        }
    }
}

// hierarchical scan, phase 1: per-block inclusive scan + block sums
__global__ __launch_bounds__(SCB) void k_scan_blk(const int* __restrict__ deg,
                                                  int* __restrict__ iscan,
                                                  int* __restrict__ bsums) {
    __shared__ int sm[SCB];
    int t = threadIdx.x;
    int j = blockIdx.x * SCB + t;
    sm[t] = (j < BN) ? deg[j] : 0;
    __syncthreads();
    for (int d = 1; d < SCB; d <<= 1) {
        int x = (t >= d) ? sm[t - d] : 0;
        __syncthreads();
        sm[t] += x;
        __syncthreads();
    }
    if (j < BN) iscan[j] = sm[t];
    if (t == SCB - 1) bsums[blockIdx.x] = sm[SCB - 1];
}

// phase 2: single-wave shfl scan of block sums (NSB <= 64)
__global__ void k_scan_top(const int* __restrict__ bsums, int* __restrict__ boffs,
                           int* __restrict__ offs) {
    int t = threadIdx.x;   // 64 threads
    int v0 = (t < NSB) ? bsums[t] : 0;
    int v = v0;
    #pragma unroll
    for (int d = 1; d < 64; d <<= 1) {
        int x = __shfl_up(v, d, 64);
        if (t >= d) v += x;
    }
    if (t < NSB) boffs[t] = v - v0;   // exclusive
    if (t == 63) offs[BN] = v;        // grand total
}

// phase 3: offs/cur = exclusive scan
__global__ __launch_bounds__(256) void k_scan_add(const int* __restrict__ iscan,
                                                  const int* __restrict__ deg,
                                                  const int* __restrict__ boffs,
                                                  int* __restrict__ offs,
                                                  int* __restrict__ cur) {
    int j = blockIdx.x * 256 + threadIdx.x;
    if (j < BN) {
        int o = iscan[j] - deg[j] + boffs[j >> 10];
        offs[j] = o;
        cur[j]  = o;
    }
}

__global__ void k_fill(const int* __restrict__ members, const void* __restrict__ maskp,
                       const int* __restrict__ flagp, int* __restrict__ cur,
                       int* __restrict__ list) {
    int flag = flagp[0];
    for (int i = blockIdx.x * blockDim.x + threadIdx.x; i < BE * Aa;
         i += gridDim.x * blockDim.x) {
        if (mask_at(maskp, flag, i) != 0.f) {
            int ge = i >> 3;
            int b = ge / Ee;
            int idx = min(max(members[i], 0), Nn - 1);
            int pos = atomicAdd(&cur[b * Nn + idx], 1);
            list[pos] = ge;
        }
    }
}

// ---------------- Edge phase (MFMA) ----------------
// EPB=32 edges/block, 256 threads = 4 waves; wave w owns cols [w*64, w*64+64).
template <bool NFBF>
__global__ __launch_bounds__(256) void k_edge(
    const float* __restrict__ nf, const u16* __restrict__ nfb,
    const int* __restrict__ members, const int* __restrict__ types,
    const void* __restrict__ maskp, const float* __restrict__ ett,
    const bf16x8* __restrict__ Wp, const float* __restrict__ benc,
    const float* __restrict__ genc, const float* __restrict__ beenc,
    const int* __restrict__ flagp, uint4* __restrict__ ef4) {
    __shared__ __align__(16) u16 s_a[EPB][LDAE];   // 18.9 KB
    __shared__ float s_red[EPB][4], s_red2[EPB][4];
    __shared__ float s_stats[EPB][2];
    __shared__ int   s_idx[EPB][Aa];
    __shared__ float s_m[EPB][Aa];
    __shared__ float s_rcnt[EPB];
    __shared__ int   s_type[EPB];

    const int tid = threadIdx.x;
    const int e0  = blockIdx.x * EPB;
    const int flag = flagp[0];
    const int w = tid >> 6, lane = tid & 63;

    {   // one (e,a) pair per thread
        int gi = e0 * Aa + tid;
        int e = tid >> 3;
        int b = (e0 + e) / Ee;
        int idx = min(max(members[gi], 0), Nn - 1);
        s_idx[e][tid & 7] = b * Nn + idx;
        s_m[e][tid & 7] = mask_at(maskp, flag, gi);
    }
    if (tid < EPB) s_type[tid] = types[e0 + tid];
    __syncthreads();
    if (tid < EPB) {
        float c = 0.f;
        #pragma unroll
        for (int a = 0; a < Aa; a++) c += s_m[tid][a];
        s_rcnt[tid] = 1.f / fmaxf(c, 1.f);
    }
    __syncthreads();

    // pooling: wave w handles 8 edges, lane owns 4 columns (8B loads, MLP=8)
    {
        const int c4 = lane * 4;
        #pragma unroll
        for (int ee = 0; ee < EPB / 4; ee++) {
            int e = w * (EPB / 4) + ee;
            float a0 = 0.f, a1 = 0.f, a2 = 0.f, a3 = 0.f;
            if (NFBF) {
                ushort4 v[Aa];
                #pragma unroll
                for (int a = 0; a < Aa; a++)
                    v[a] = *(const ushort4*)(nfb + (size_t)s_idx[e][a] * Hh + c4);
                #pragma unroll
                for (int a = 0; a < Aa; a++) {
                    float mm = s_m[e][a];
                    a0 = fmaf(mm, bf2f(v[a].x), a0);
                    a1 = fmaf(mm, bf2f(v[a].y), a1);
                    a2 = fmaf(mm, bf2f(v[a].z), a2);
                    a3 = fmaf(mm, bf2f(v[a].w), a3);
                }
            } else {
                float4 v[Aa];
                #pragma unroll
                for (int a = 0; a < Aa; a++)
                    v[a] = *(const float4*)(nf + (size_t)s_idx[e][a] * Hh + c4);
                #pragma unroll
                for (int a = 0; a < Aa; a++) {
                    float mm = s_m[e][a];
                    a0 = fmaf(mm, v[a].x, a0);
                    a1 = fmaf(mm, v[a].y, a1);
                    a2 = fmaf(mm, v[a].z, a2);
                    a3 = fmaf(mm, v[a].w, a3);
                }
            }
            float rc = s_rcnt[e];
            ushort4 o;
            o.x = f2bf(a0 * rc); o.y = f2bf(a1 * rc);
            o.z = f2bf(a2 * rc); o.w = f2bf(a3 * rc);
            *(ushort4*)&s_a[e][c4] = o;
        }
        // type embedding cols 256..287
        #pragma unroll
        for (int i = tid; i < EPB * TEe; i += 256) {
            int e = i >> 5, cc = i & 31;
            s_a[e][Hh + cc] = f2bf(ett[s_type[e] * TEe + cc]);
        }
    }
    __syncthreads();

    const int l15 = lane & 15, lg = lane >> 4;

    f32x4 acc[2][4];
    #pragma unroll
    for (int m = 0; m < 2; m++)
        #pragma unroll
        for (int n = 0; n < 4; n++) acc[m][n] = (f32x4){0.f, 0.f, 0.f, 0.f};

    for (int kt = 0; kt < KTE; kt++) {
        bf16x8 bfr[4], afr[2];
        #pragma unroll
        for (int n = 0; n < 4; n++)
            bfr[n] = Wp[((size_t)((w * 4 + n) * KTE + kt)) * 64 + lane];
        #pragma unroll
        for (int m = 0; m < 2; m++)
            afr[m] = *(const bf16x8*)&s_a[m * 16 + l15][kt * 32 + lg * 8];
        #pragma unroll
        for (int m = 0; m < 2; m++)
            #pragma unroll
            for (int n = 0; n < 4; n++)
                acc[m][n] = mfma16(afr[m], bfr[n], acc[m][n]);
    }

    float bia[4], gam[4], bet[4];
    #pragma unroll
    for (int n = 0; n < 4; n++) bia[n] = benc[w * 64 + n * 16 + l15];
    #pragma unroll
    for (int m = 0; m < 2; m++)
        #pragma unroll
        for (int n = 0; n < 4; n++)
            #pragma unroll
            for (int j = 0; j < 4; j++)
                acc[m][n][j] = gelu_f(acc[m][n][j] + bia[n]);

    #pragma unroll
    for (int m = 0; m < 2; m++)
        #pragma unroll
        for (int j = 0; j < 4; j++) {
            float s = 0.f, s2 = 0.f;
            #pragma unroll
            for (int n = 0; n < 4; n++) {
                float v = acc[m][n][j];
                s += v; s2 = fmaf(v, v, s2);
            }
            #pragma unroll
            for (int mk = 1; mk < 16; mk <<= 1) {
                s  += __shfl_xor(s, mk, 64);
                s2 += __shfl_xor(s2, mk, 64);
            }
            if (l15 == 0) {
                int r = m * 16 + lg * 4 + j;
                s_red[r][w] = s; s_red2[r][w] = s2;
            }
        }
    __syncthreads();
    if (tid < EPB) {
        float s  = s_red[tid][0] + s_red[tid][1] + s_red[tid][2] + s_red[tid][3];
        float s2 = s_red2[tid][0] + s_red2[tid][1] + s_red2[tid][2] + s_red2[tid][3];
        float mu = s * (1.f / Hh);
        float var = s2 * (1.f / Hh) - mu * mu;
        s_stats[tid][0] = mu;
        s_stats[tid][1] = rsqrtf(var + 1e-5f);
    }
    __syncthreads();
    #pragma unroll
    for (int n = 0; n < 4; n++) {
        int col = w * 64 + n * 16 + l15;
        gam[n] = genc[col]; bet[n] = beenc[col];
    }
    #pragma unroll
    for (int m = 0; m < 2; m++)
        #pragma unroll
        for (int j = 0; j < 4; j++) {
            int r = m * 16 + lg * 4 + j;
            float mu = s_stats[r][0], rs = s_stats[r][1];
            #pragma unroll
            for (int n = 0; n < 4; n++) {
                float val = (acc[m][n][j] - mu) * rs * gam[n] + bet[n];
                s_a[r][w * 64 + n * 16 + l15] = f2bf(val);
            }
        }
    __syncthreads();

    const uint4* sa4 = (const uint4*)&s_a[0][0];   // row stride 37 uint4
    #pragma unroll
    for (int i = 0; i < 4; i++) {
        int idx = i * 256 + tid;
        int r = idx >> 5, cc = idx & 31;
        ef4[(size_t)(e0 + r) * 32 + cc] = sa4[r * 37 + cc];
    }
}

// ---------------- Node phase (MFMA) ----------------
template <bool NFBF>
__global__ __launch_bounds__(256) void k_node(
    const float* __restrict__ nf, const u16* __restrict__ nfb,
    const u16* __restrict__ efb, const int* __restrict__ offs,
    const int* __restrict__ list, const bf16x8* __restrict__ Wp,
    const float* __restrict__ bupd, const float* __restrict__ gupd,
    const float* __restrict__ beupd, float* __restrict__ out) {
    __shared__ __align__(16) u16 s_a[NPB][LDAU];   // 33.3 KB
    __shared__ float s_red[NPB][4], s_red2[NPB][4];
    __shared__ float s_stats[NPB][2];
    __shared__ int   s_offs[NPB + 1];
    __shared__ int   s_list[SLCAP + 8];

    const int tid = threadIdx.x;
    const int n0  = blockIdx.x * NPB;
    const int w = tid >> 6, lane = tid & 63;

    if (tid < NPB + 1) s_offs[tid] = offs[n0 + tid];
    __syncthreads();
    const int segbase = s_offs[0];
    const int segtot  = s_offs[NPB] - segbase;
    const bool staged = segtot <= SLCAP;
    if (staged)
        for (int j = tid; j < segtot; j += 256) s_list[j] = list[segbase + j];

    // stage nf half of A (cols 0..255)
    if (NFBF) {
        uint4* saw = (uint4*)&s_a[0][0];           // row stride 65 uint4
        const uint4* nf4 = (const uint4*)nfb + (size_t)n0 * 32;
        #pragma unroll
        for (int i = 0; i < 4; i++) {
            int idx = i * 256 + tid;
            int r = idx >> 5, cc = idx & 31;
            saw[r * 65 + cc] = nf4[r * 32 + cc];
        }
    } else {
        const float4* nf4 = (const float4*)nf + (size_t)n0 * 64;
        #pragma unroll
        for (int i = 0; i < 8; i++) {
            int idx = i * 256 + tid;
            int r = idx >> 6, c4 = idx & 63;
            float4 v = nf4[r * 64 + c4];
            ushort4 u; u.x = f2bf(v.x); u.y = f2bf(v.y); u.z = f2bf(v.z); u.w = f2bf(v.w);
            *(ushort4*)&s_a[r][c4 * 4] = u;
        }
    }
    __syncthreads();   // s_list + nf staging complete

    // gather upd half (cols 256..511): wave w handles 8 nodes, lane owns 4 cols
    {
        const int c4 = lane * 4;
        #pragma unroll
        for (int ii = 0; ii < NPB / 4; ii++) {
            int i = w * (NPB / 4) + ii;
            int o0 = s_offs[i] - segbase;
            int d  = s_offs[i + 1] - s_offs[i];
            float a0 = 0.f, a1 = 0.f, a2 = 0.f, a3 = 0.f;
            for (int j0 = 0; j0 < d; j0 += 8) {
                ushort4 v[8];
                #pragma unroll
                for (int q = 0; q < 8; q++) {
                    int j = j0 + q;
                    int ge;
                    if (staged) ge = (j < d) ? s_list[o0 + j] : BE;
                    else        ge = (j < d) ? list[segbase + o0 + j] : BE;
                    v[q] = *(const ushort4*)(efb + (size_t)ge * Hh + c4);
                }
                #pragma unroll
                for (int q = 0; q < 8; q++) {
                    a0 += bf2f(v[q].x); a1 += bf2f(v[q].y);
                    a2 += bf2f(v[q].z); a3 += bf2f(v[q].w);
                }
            }
            float rc = 1.f / fmaxf((float)d, 1.f);
            ushort4 o;
            o.x = f2bf(a0 * rc); o.y = f2bf(a1 * rc);
            o.z = f2bf(a2 * rc); o.w = f2bf(a3 * rc);
            *(ushort4*)&s_a[i][Hh + c4] = o;
        }
    }
    __syncthreads();

    const int l15 = lane & 15, lg = lane >> 4;

    f32x4 acc[2][4];
    #pragma unroll
    for (int m = 0; m < 2; m++)
        #pragma unroll
        for (int n = 0; n < 4; n++) acc[m][n] = (f32x4){0.f, 0.f, 0.f, 0.f};

    for (int kt = 0; kt < KTU; kt++) {
        bf16x8 bfr[4], afr[2];
        #pragma unroll
        for (int n = 0; n < 4; n++)
            bfr[n] = Wp[((size_t)((w * 4 + n) * KTU + kt)) * 64 + lane];
        #pragma unroll
        for (int m = 0; m < 2; m++)
            afr[m] = *(const bf16x8*)&s_a[m * 16 + l15][kt * 32 + lg * 8];
        #pragma unroll
        for (int m = 0; m < 2; m++)
            #pragma unroll
            for (int n = 0; n < 4; n++)
                acc[m][n] = mfma16(afr[m], bfr[n], acc[m][n]);
    }

    float bia[4], gam[4], bet[4];
    #pragma unroll
    for (int n = 0; n < 4; n++) bia[n] = bupd[w * 64 + n * 16 + l15];
    #pragma unroll
    for (int m = 0; m < 2; m++)
        #pragma unroll
        for (int n = 0; n < 4; n++)
            #pragma unroll
            for (int j = 0; j < 4; j++)
                acc[m][n][j] = gelu_f(acc[m][n][j] + bia[n]);

    #pragma unroll
    for (int m = 0; m < 2; m++)
        #pragma unroll
        for (int j = 0; j < 4; j++) {
            float s = 0.f, s2 = 0.f;
            #pragma unroll
            for (int n = 0; n < 4; n++) {
                float v = acc[m][n][j];
                s += v; s2 = fmaf(v, v, s2);
            }
            #pragma unroll
            for (int mk = 1; mk < 16; mk <<= 1) {
                s  += __shfl_xor(s, mk, 64);
                s2 += __shfl_xor(s2, mk, 64);
            }
            if (l15 == 0) {
                int r = m * 16 + lg * 4 + j;
                s_red[r][w] = s; s_red2[r][w] = s2;
            }
        }
    __syncthreads();
    if (tid < NPB) {
        float s  = s_red[tid][0] + s_red[tid][1] + s_red[tid][2] + s_red[tid][3];
        float s2 = s_red2[tid][0] + s_red2[tid][1] + s_red2[tid][2] + s_red2[tid][3];
        float mu = s * (1.f / Hh);
        float var = s2 * (1.f / Hh) - mu * mu;
        s_stats[tid][0] = mu;
        s_stats[tid][1] = rsqrtf(var + 1e-5f);
    }
    __syncthreads();
    #pragma unroll
    for (int n = 0; n < 4; n++) {
        int col = w * 64 + n * 16 + l15;
        gam[n] = gupd[col]; bet[n] = beupd[col];
    }
    float* s_f = (float*)&s_a[0][0];   // reuse as f32, row stride 260
    #pragma unroll
    for (int m = 0; m < 2; m++)
        #pragma unroll
        for (int j = 0; j < 4; j++) {
            int r = m * 16 + lg * 4 + j;
            float mu = s_stats[r][0], rs = s_stats[r][1];
            #pragma unroll
            for (int n = 0; n < 4; n++) {
                float val = (acc[m][n][j] - mu) * rs * gam[n] + bet[n];
                s_f[r * 260 + w * 64 + n * 16 + l15] = val;
            }
        }
    __syncthreads();
    const float4* sf4 = (const float4*)s_f;        // row stride 65 float4
    float4* out4 = (float4*)out + (size_t)n0 * 64;
    #pragma unroll
    for (int i = 0; i < 8; i++) {
        int idx = i * 256 + tid;
        int r = idx >> 6, c4 = idx & 63;
        out4[r * 64 + c4] = sf4[r * 65 + c4];
    }
}

extern "C" void kernel_launch(void* const* d_in, const int* in_sizes, int n_in,
                              void* d_out, int out_size, void* d_ws, size_t ws_size,
                              hipStream_t stream) {
    const float* nf    = (const float*)d_in[0];
    const int* members = (const int*)d_in[1];
    const int* types   = (const int*)d_in[2];
    const void* maskp  = d_in[3];
    const float* ett   = (const float*)d_in[4];
    const float* Wenc  = (const float*)d_in[5];
    const float* benc  = (const float*)d_in[6];
    const float* genc  = (const float*)d_in[7];
    const float* beenc = (const float*)d_in[8];
    const float* Wupd  = (const float*)d_in[9];
    const float* bupd  = (const float*)d_in[10];
    const float* gupd  = (const float*)d_in[11];
    const float* beupd = (const float*)d_in[12];
    float* out = (float*)d_out;

    // workspace layout
    int* ip    = (int*)d_ws;
    int* flag  = ip;                      // 64 ints
    int* deg   = ip + 64;                 // BN
    int* offs  = deg + BN;                // BN+16
    int* cur   = offs + BN + 16;          // BN
    int* iscan = cur + BN;                // BN
    int* bsums = iscan + BN;              // 64
    int* boffs = bsums + 64;              // 64
    int* list  = boffs + 64;              // BE*Aa + 16
    char* p   = (char*)(list + BE * Aa + 16);
    u16* efb    = (u16*)p;                p += (size_t)(BE + 1) * Hh * 2;  // +zero row
    u16* WencP  = (u16*)p;                p += (size_t)16 * KTE * 64 * 8 * 2;
    u16* WupdP  = (u16*)p;                p += (size_t)16 * KTU * 64 * 8 * 2;
    u16* nfb    = (u16*)p;                p += (size_t)BN * Hh * 2;
    const bool use_nfbf = ((size_t)(p - (char*)d_ws) <= ws_size);

    int n4 = (64 + BN) / 4;
    hipLaunchKernelGGL(k_zero, dim3(64), dim3(256), 0, stream, (float4*)ip, n4);
    // zero the dummy efb row (row BE)
    hipLaunchKernelGGL(k_zero, dim3(1), dim3(64), 0, stream,
                       (float4*)(efb + (size_t)BE * Hh), Hh * 2 / 16);
    hipLaunchKernelGGL(k_detect, dim3(256), dim3(256), 0, stream,
                       (const unsigned int*)maskp, BE * Aa / 4, flag);
    if (use_nfbf)
        hipLaunchKernelGGL(k_cvt, dim3(2048), dim3(256), 0, stream,
                           (const float4*)nf, (ushort4*)nfb, BN * Hh / 4);
    hipLaunchKernelGGL(k_pack, dim3(36), dim3(256), 0, stream,
                       Wenc, WencP, KTE, 16 * KTE * 64);
    hipLaunchKernelGGL(k_pack, dim3(64), dim3(256), 0, stream,
                       Wupd, WupdP, KTU, 16 * KTU * 64);
    hipLaunchKernelGGL(k_count, dim3(640), dim3(256), 0, stream,
                       members, maskp, flag, deg);
    hipLaunchKernelGGL(k_scan_blk, dim3(NSB), dim3(SCB), 0, stream,
                       deg, iscan, bsums);
    hipLaunchKernelGGL(k_scan_top, dim3(1), dim3(64), 0, stream,
                       bsums, boffs, offs);
    hipLaunchKernelGGL(k_scan_add, dim3((BN + 255) / 256), dim3(256), 0, stream,
                       iscan, deg, boffs, offs, cur);
    hipLaunchKernelGGL(k_fill, dim3(640), dim3(256), 0, stream,
                       members, maskp, flag, cur, list);
    if (use_nfbf) {
        hipLaunchKernelGGL((k_edge<true>), dim3(BE / EPB), dim3(256), 0, stream,
                           nf, nfb, members, types, maskp, ett,
                           (const bf16x8*)WencP, benc, genc, beenc, flag,
                           (uint4*)efb);
        hipLaunchKernelGGL((k_node<true>), dim3(BN / NPB), dim3(256), 0, stream,
                           nf, nfb, efb, offs, list, (const bf16x8*)WupdP,
                           bupd, gupd, beupd, out);
    } else {
        hipLaunchKernelGGL((k_edge<false>), dim3(BE / EPB), dim3(256), 0, stream,
                           nf, nfb, members, types, maskp, ett,
                           (const bf16x8*)WencP, benc, genc, beenc, flag,
                           (uint4*)efb);
        hipLaunchKernelGGL((k_node<false>), dim3(BN / NPB), dim3(256), 0, stream,
                           nf, nfb, efb, offs, list, (const bf16x8*)WupdP,
                           bupd, gupd, beupd, out);
    }
}

// Round 6
// 179.169 us; speedup vs baseline: 5.3236x; 1.0430x over previous
//
#include <hip/hip_runtime.h>
#include <math.h>

// Problem constants
#define Bq 2
#define Nn 20000
#define Ee 20000
#define Aa 8
#define Hh 256
#define TEe 32
#define NTy 16
constexpr int BE   = Bq * Ee;    // 40000
constexpr int BN   = Bq * Nn;    // 40000
constexpr int KTE  = 8;          // edge GEMM K-tiles (256/32)
constexpr int KTU  = 16;         // node GEMM K-tiles (512/32)
constexpr int LDAE = 264;        // padded edge A row (ushorts) = 33 uint4
constexpr int LDAU = 520;        // padded node A row (ushorts) = 65 uint4
constexpr int SCB  = 1024;       // scan block size
constexpr int NSB  = (BN + SCB - 1) / SCB;   // 40

typedef __attribute__((ext_vector_type(8))) short bf16x8;
typedef __attribute__((ext_vector_type(4))) float f32x4;
typedef unsigned short u16;
typedef unsigned int   u32;

__device__ __forceinline__ u16 f2bf(float f) {           // RNE f32 -> bf16
    u32 u = __float_as_uint(f);
    u32 r = u + 0x7FFFu + ((u >> 16) & 1u);
    return (u16)(r >> 16);
}
__device__ __forceinline__ float bf2f(u16 h) {
    return __uint_as_float(((u32)h) << 16);
}
__device__ __forceinline__ float gelu_f(float x) {
    return 0.5f * x * (1.f + erff(x * 0.70710678118654752440f));
}
__device__ __forceinline__ f32x4 mfma16(bf16x8 a, bf16x8 b, f32x4 c) {
    return __builtin_amdgcn_mfma_f32_16x16x32_bf16(a, b, c, 0, 0, 0);
}

// mask dtype sniffing: bit1 => f32 mask, bit0 => u8 mask, none => i32
__device__ __forceinline__ float mask_at(const void* mp, int flag, int i) {
    if (flag & 2) return ((const float*)mp)[i];
    if (flag & 1) return ((const unsigned char*)mp)[i] ? 1.f : 0.f;
    return ((const int*)mp)[i] ? 1.f : 0.f;
}

__global__ void k_zero(float4* p, int n4) {
    int i = blockIdx.x * blockDim.x + threadIdx.x;
    int stride = gridDim.x * blockDim.x;
    float4 z; z.x = 0.f; z.y = 0.f; z.z = 0.f; z.w = 0.f;
    for (; i < n4; i += stride) p[i] = z;
}

__global__ void k_detect(const unsigned int* mw, int n, int* flag) {
    int found = 0;
    for (int i = blockIdx.x * blockDim.x + threadIdx.x; i < n;
         i += gridDim.x * blockDim.x) {
        unsigned int w = mw[i];
        if (w == 0x3F800000u) found |= 2;
        else if (w > 1u) found |= 1;
    }
    __shared__ int sf;
    if (threadIdx.x == 0) sf = 0;
    __syncthreads();
    if (found) atomicOr(&sf, found);
    __syncthreads();
    if (threadIdx.x == 0 && sf) atomicOr(flag, sf);
}

__global__ void k_cvt(const float4* __restrict__ in, ushort4* __restrict__ o, int n4) {
    for (int i = blockIdx.x * blockDim.x + threadIdx.x; i < n4;
         i += gridDim.x * blockDim.x) {
        float4 v = in[i];
        ushort4 u; u.x = f2bf(v.x); u.y = f2bf(v.y); u.z = f2bf(v.z); u.w = f2bf(v.w);
        o[i] = u;
    }
}

// pack W [K][256] f32 into MFMA B-fragment order (KT k-tiles of 32)
__global__ void k_pack(const float* __restrict__ W, u16* __restrict__ Wp,
                       int KT, int nthreads) {
    int t = blockIdx.x * blockDim.x + threadIdx.x;
    if (t >= nthreads) return;
    int lane = t & 63, tile = t >> 6;
    int kt = tile % KT, nt = tile / KT;
    int kbase = kt * 32 + (lane >> 4) * 8;
    int col = nt * 16 + (lane & 15);
    u16 tmp[8];
    #pragma unroll
    for (int j = 0; j < 8; j++) tmp[j] = f2bf(W[(size_t)(kbase + j) * Hh + col]);
    *(uint4*)(Wp + (size_t)t * 8) = *(const uint4*)tmp;
}

// type_bias[t][col] = b_enc[col] + sum_k ett[t][k] * Wenc[256+k][col]
__global__ __launch_bounds__(256) void k_prep_tb(const float* __restrict__ ett,
                                                 const float* __restrict__ Wenc,
                                                 const float* __restrict__ benc,
                                                 float* __restrict__ tb) {
    __shared__ float s_e[NTy * TEe];
    int tid = threadIdx.x;
    for (int i = tid; i < NTy * TEe; i += 256) s_e[i] = ett[i];
    __syncthreads();
    float b = benc[tid];
    for (int t = 0; t < NTy; t++) {
        float acc = b;
        #pragma unroll 8
        for (int k = 0; k < TEe; k++)
            acc = fmaf(s_e[t * TEe + k], Wenc[(size_t)(Hh + k) * Hh + tid], acc);
        tb[t * Hh + tid] = acc;
    }
}

__global__ void k_count(const int* __restrict__ members, const void* __restrict__ maskp,
                        const int* __restrict__ flagp, int* __restrict__ deg) {
    int flag = flagp[0];
    for (int i = blockIdx.x * blockDim.x + threadIdx.x; i < BE * Aa;
         i += gridDim.x * blockDim.x) {
        if (mask_at(maskp, flag, i) != 0.f) {
            int ge = i >> 3;
            int b = ge / Ee;
            int idx = min(max(members[i], 0), Nn - 1);
            atomicAdd(&deg[b * Nn + idx], 1);
        }
    }
}

__global__ __launch_bounds__(SCB) void k_scan_blk(const int* __restrict__ deg,
                                                  int* __restrict__ iscan,
                                                  int* __restrict__ bsums) {
    __shared__ int sm[SCB];
    int t = threadIdx.x;
    int j = blockIdx.x * SCB + t;
    sm[t] = (j < BN) ? deg[j] : 0;
    __syncthreads();
    for (int d = 1; d < SCB; d <<= 1) {
        int x = (t >= d) ? sm[t - d] : 0;
        __syncthreads();
        sm[t] += x;
        __syncthreads();
    }
    if (j < BN) iscan[j] = sm[t];
    if (t == SCB - 1) bsums[blockIdx.x] = sm[SCB - 1];
}

__global__ void k_scan_top(const int* __restrict__ bsums, int* __restrict__ boffs,
                           int* __restrict__ offs) {
    int t = threadIdx.x;   // 64 threads
    int v0 = (t < NSB) ? bsums[t] : 0;
    int v = v0;
    #pragma unroll
    for (int d = 1; d < 64; d <<= 1) {
        int x = __shfl_up(v, d, 64);
        if (t >= d) v += x;
    }
    if (t < NSB) boffs[t] = v - v0;   // exclusive
    if (t == 63) offs[BN] = v;        // grand total
}

__global__ __launch_bounds__(256) void k_scan_add(const int* __restrict__ iscan,
                                                  const int* __restrict__ deg,
                                                  const int* __restrict__ boffs,
                                                  int* __restrict__ offs,
                                                  int* __restrict__ cur) {
    int j = blockIdx.x * 256 + threadIdx.x;
    if (j < BN) {
        int o = iscan[j] - deg[j] + boffs[j >> 10];
        offs[j] = o;
        cur[j]  = o;
    }
}

__global__ void k_fill(const int* __restrict__ members, const void* __restrict__ maskp,
                       const int* __restrict__ flagp, int* __restrict__ cur,
                       int* __restrict__ list) {
    int flag = flagp[0];
    for (int i = blockIdx.x * blockDim.x + threadIdx.x; i < BE * Aa;
         i += gridDim.x * blockDim.x) {
        if (mask_at(maskp, flag, i) != 0.f) {
            int ge = i >> 3;
            int b = ge / Ee;
            int idx = min(max(members[i], 0), Nn - 1);
            int pos = atomicAdd(&cur[b * Nn + idx], 1);
            list[pos] = ge;
        }
    }
}

// -------- Edge pooling gather: one wave per edge, max occupancy --------
template <bool NFBF>
__global__ __launch_bounds__(512) void k_gath_edge(
    const float* __restrict__ nf, const u16* __restrict__ nfb,
    const int* __restrict__ members, const void* __restrict__ maskp,
    const int* __restrict__ flagp, u16* __restrict__ pooled) {
    const int e = (blockIdx.x * 512 + threadIdx.x) >> 6;
    const int lane = threadIdx.x & 63;
    if (e >= BE) return;
    const int flag = flagp[0];

    int mem = 0; float mv = 0.f;
    if (lane < Aa) {
        int gi = e * Aa + lane;
        mem = min(max(members[gi], 0), Nn - 1) + ((e >= Ee) ? Nn : 0);
        mv = mask_at(maskp, flag, gi);
    }
    int idx[Aa]; float m[Aa];
    #pragma unroll
    for (int a = 0; a < Aa; a++) {
        idx[a] = __shfl(mem, a, 64);
        m[a]   = __shfl(mv, a, 64);
    }
    float c = 0.f;
    #pragma unroll
    for (int a = 0; a < Aa; a++) c += m[a];
    const float rc = 1.f / fmaxf(c, 1.f);

    const int c4 = lane * 4;
    float a0 = 0.f, a1 = 0.f, a2 = 0.f, a3 = 0.f;
    if (NFBF) {
        ushort4 v[Aa];
        #pragma unroll
        for (int a = 0; a < Aa; a++)
            v[a] = *(const ushort4*)(nfb + (size_t)idx[a] * Hh + c4);
        #pragma unroll
        for (int a = 0; a < Aa; a++) {
            a0 = fmaf(m[a], bf2f(v[a].x), a0);
            a1 = fmaf(m[a], bf2f(v[a].y), a1);
            a2 = fmaf(m[a], bf2f(v[a].z), a2);
            a3 = fmaf(m[a], bf2f(v[a].w), a3);
        }
    } else {
        float4 v[Aa];
        #pragma unroll
        for (int a = 0; a < Aa; a++)
            v[a] = *(const float4*)(nf + (size_t)idx[a] * Hh + c4);
        #pragma unroll
        for (int a = 0; a < Aa; a++) {
            a0 = fmaf(m[a], v[a].x, a0);
            a1 = fmaf(m[a], v[a].y, a1);
            a2 = fmaf(m[a], v[a].z, a2);
            a3 = fmaf(m[a], v[a].w, a3);
        }
    }
    ushort4 o;
    o.x = f2bf(a0 * rc); o.y = f2bf(a1 * rc);
    o.z = f2bf(a2 * rc); o.w = f2bf(a3 * rc);
    *(ushort4*)(pooled + (size_t)e * Hh + c4) = o;
}

// -------- Node update gather: one wave per node --------
__global__ __launch_bounds__(512) void k_gath_node(
    const u16* __restrict__ efb, const int* __restrict__ offs,
    const int* __restrict__ list, u16* __restrict__ updb) {
    const int n = (blockIdx.x * 512 + threadIdx.x) >> 6;
    const int lane = threadIdx.x & 63;
    if (n >= BN) return;
    const int o0 = offs[n];
    const int d  = offs[n + 1] - o0;
    const int c4 = lane * 4;
    float a0 = 0.f, a1 = 0.f, a2 = 0.f, a3 = 0.f;
    for (int j0 = 0; j0 < d; j0 += 8) {
        int lv = (lane < 8 && (j0 + lane) < d) ? list[o0 + j0 + lane] : BE;
        ushort4 v[8];
        #pragma unroll
        for (int q = 0; q < 8; q++) {
            int ge = __shfl(lv, q, 64);
            v[q] = *(const ushort4*)(efb + (size_t)ge * Hh + c4);
        }
        #pragma unroll
        for (int q = 0; q < 8; q++) {
            a0 += bf2f(v[q].x); a1 += bf2f(v[q].y);
            a2 += bf2f(v[q].z); a3 += bf2f(v[q].w);
        }
    }
    const float rc = 1.f / fmaxf((float)d, 1.f);
    ushort4 o;
    o.x = f2bf(a0 * rc); o.y = f2bf(a1 * rc);
    o.z = f2bf(a2 * rc); o.w = f2bf(a3 * rc);
    *(ushort4*)(updb + (size_t)n * Hh + c4) = o;
}

// -------- Edge GEMM: x = pooled @ We1 + type_bias -> gelu -> LN -> efb --------
__global__ __launch_bounds__(256) void k_gemm_edge(
    const u16* __restrict__ pooled, const int* __restrict__ types,
    const bf16x8* __restrict__ Wp, const float* __restrict__ tb,
    const float* __restrict__ genc, const float* __restrict__ beenc,
    uint4* __restrict__ ef4) {
    __shared__ __align__(16) u16 s_a[32][LDAE];   // 16.5 KB
    __shared__ float s_red[32][4], s_red2[32][4];
    __shared__ float s_stats[32][2];
    __shared__ int   s_type[32];

    const int tid = threadIdx.x;
    const int e0  = blockIdx.x * 32;
    const int w = tid >> 6, lane = tid & 63;
    const int l15 = lane & 15, lg = lane >> 4;

    if (tid < 32) s_type[tid] = types[e0 + tid];
    {   // stage A (bf16, contiguous)
        uint4* saw = (uint4*)&s_a[0][0];           // row stride 33 uint4
        const uint4* src = (const uint4*)pooled + (size_t)e0 * 32;
        #pragma unroll
        for (int i = 0; i < 4; i++) {
            int idx = i * 256 + tid;
            int r = idx >> 5, cc = idx & 31;
            saw[r * 33 + cc] = src[r * 32 + cc];
        }
    }
    __syncthreads();

    f32x4 acc[2][4];
    #pragma unroll
    for (int m = 0; m < 2; m++)
        #pragma unroll
        for (int n = 0; n < 4; n++) acc[m][n] = (f32x4){0.f, 0.f, 0.f, 0.f};

    for (int kt = 0; kt < KTE; kt++) {
        bf16x8 bfr[4], afr[2];
        #pragma unroll
        for (int n = 0; n < 4; n++)
            bfr[n] = Wp[((size_t)((w * 4 + n) * KTE + kt)) * 64 + lane];
        #pragma unroll
        for (int m = 0; m < 2; m++)
            afr[m] = *(const bf16x8*)&s_a[m * 16 + l15][kt * 32 + lg * 8];
        #pragma unroll
        for (int m = 0; m < 2; m++)
            #pragma unroll
            for (int n = 0; n < 4; n++)
                acc[m][n] = mfma16(afr[m], bfr[n], acc[m][n]);
    }

    // + type_bias, gelu
    #pragma unroll
    for (int m = 0; m < 2; m++)
        #pragma unroll
        for (int j = 0; j < 4; j++) {
            int r = m * 16 + lg * 4 + j;
            int t = s_type[r];
            #pragma unroll
            for (int n = 0; n < 4; n++) {
                int col = w * 64 + n * 16 + l15;
                acc[m][n][j] = gelu_f(acc[m][n][j] + tb[t * Hh + col]);
            }
        }

    #pragma unroll
    for (int m = 0; m < 2; m++)
        #pragma unroll
        for (int j = 0; j < 4; j++) {
            float s = 0.f, s2 = 0.f;
            #pragma unroll
            for (int n = 0; n < 4; n++) {
                float v = acc[m][n][j];
                s += v; s2 = fmaf(v, v, s2);
            }
            #pragma unroll
            for (int mk = 1; mk < 16; mk <<= 1) {
                s  += __shfl_xor(s, mk, 64);
                s2 += __shfl_xor(s2, mk, 64);
            }
            if (l15 == 0) {
                int r = m * 16 + lg * 4 + j;
                s_red[r][w] = s; s_red2[r][w] = s2;
            }
        }
    __syncthreads();
    if (tid < 32) {
        float s  = s_red[tid][0] + s_red[tid][1] + s_red[tid][2] + s_red[tid][3];
        float s2 = s_red2[tid][0] + s_red2[tid][1] + s_red2[tid][2] + s_red2[tid][3];
        float mu = s * (1.f / Hh);
        float var = s2 * (1.f / Hh) - mu * mu;
        s_stats[tid][0] = mu;
        s_stats[tid][1] = rsqrtf(var + 1e-5f);
    }
    __syncthreads();
    float gam[4], bet[4];
    #pragma unroll
    for (int n = 0; n < 4; n++) {
        int col = w * 64 + n * 16 + l15;
        gam[n] = genc[col]; bet[n] = beenc[col];
    }
    #pragma unroll
    for (int m = 0; m < 2; m++)
        #pragma unroll
        for (int j = 0; j < 4; j++) {
            int r = m * 16 + lg * 4 + j;
            float mu = s_stats[r][0], rs = s_stats[r][1];
            #pragma unroll
            for (int n = 0; n < 4; n++) {
                float val = (acc[m][n][j] - mu) * rs * gam[n] + bet[n];
                s_a[r][w * 64 + n * 16 + l15] = f2bf(val);
            }
        }
    __syncthreads();
    const uint4* sa4 = (const uint4*)&s_a[0][0];
    #pragma unroll
    for (int i = 0; i < 4; i++) {
        int idx = i * 256 + tid;
        int r = idx >> 5, cc = idx & 31;
        ef4[(size_t)(e0 + r) * 32 + cc] = sa4[r * 33 + cc];
    }
}

// -------- Node GEMM: y = [nf | updb] @ Wupd + b -> gelu -> LN -> out --------
template <bool NFBF>
__global__ __launch_bounds__(256) void k_gemm_node(
    const float* __restrict__ nf, const u16* __restrict__ nfb,
    const u16* __restrict__ updb, const bf16x8* __restrict__ Wp,
    const float* __restrict__ bupd, const float* __restrict__ gupd,
    const float* __restrict__ beupd, float* __restrict__ out) {
    __shared__ __align__(16) u16 s_a[32][LDAU];   // 33.3 KB
    __shared__ float s_red[32][4], s_red2[32][4];
    __shared__ float s_stats[32][2];

    const int tid = threadIdx.x;
    const int n0  = blockIdx.x * 32;
    const int w = tid >> 6, lane = tid & 63;
    const int l15 = lane & 15, lg = lane >> 4;

    {   // stage A: nf half (cols 0-255), updb half (cols 256-511)
        uint4* saw = (uint4*)&s_a[0][0];           // row stride 65 uint4
        const uint4* upd4 = (const uint4*)updb + (size_t)n0 * 32;
        if (NFBF) {
            const uint4* nf4 = (const uint4*)nfb + (size_t)n0 * 32;
            #pragma unroll
            for (int i = 0; i < 4; i++) {
                int idx = i * 256 + tid;
                int r = idx >> 5, cc = idx & 31;
                saw[r * 65 + cc] = nf4[r * 32 + cc];
            }
        } else {
            const float4* nf4 = (const float4*)nf + (size_t)n0 * 64;
            #pragma unroll
            for (int i = 0; i < 8; i++) {
                int idx = i * 256 + tid;
                int r = idx >> 6, c4 = idx & 63;
                float4 v = nf4[r * 64 + c4];
                ushort4 u; u.x = f2bf(v.x); u.y = f2bf(v.y);
                u.z = f2bf(v.z); u.w = f2bf(v.w);
                *(ushort4*)&s_a[r][c4 * 4] = u;
            }
        }
        #pragma unroll
        for (int i = 0; i < 4; i++) {
            int idx = i * 256 + tid;
            int r = idx >> 5, cc = idx & 31;
            saw[r * 65 + 32 + cc] = upd4[r * 32 + cc];
        }
    }
    __syncthreads();

    f32x4 acc[2][4];
    #pragma unroll
    for (int m = 0; m < 2; m++)
        #pragma unroll
        for (int n = 0; n < 4; n++) acc[m][n] = (f32x4){0.f, 0.f, 0.f, 0.f};

    for (int kt = 0; kt < KTU; kt++) {
        bf16x8 bfr[4], afr[2];
        #pragma unroll
        for (int n = 0; n < 4; n++)
            bfr[n] = Wp[((size_t)((w * 4 + n) * KTU + kt)) * 64 + lane];
        #pragma unroll
        for (int m = 0; m < 2; m++)
            afr[m] = *(const bf16x8*)&s_a[m * 16 + l15][kt * 32 + lg * 8];
        #pragma unroll
        for (int m = 0; m < 2; m++)
            #pragma unroll
            for (int n = 0; n < 4; n++)
                acc[m][n] = mfma16(afr[m], bfr[n], acc[m][n]);
    }

    float bia[4], gam[4], bet[4];
    #pragma unroll
    for (int n = 0; n < 4; n++) bia[n] = bupd[w * 64 + n * 16 + l15];
    #pragma unroll
    for (int m = 0; m < 2; m++)
        #pragma unroll
        for (int n = 0; n < 4; n++)
            #pragma unroll
            for (int j = 0; j < 4; j++)
                acc[m][n][j] = gelu_f(acc[m][n][j] + bia[n]);

    #pragma unroll
    for (int m = 0; m < 2; m++)
        #pragma unroll
        for (int j = 0; j < 4; j++) {
            float s = 0.f, s2 = 0.f;
            #pragma unroll
            for (int n = 0; n < 4; n++) {
                float v = acc[m][n][j];
                s += v; s2 = fmaf(v, v, s2);
            }
            #pragma unroll
            for (int mk = 1; mk < 16; mk <<= 1) {
                s  += __shfl_xor(s, mk, 64);
                s2 += __shfl_xor(s2, mk, 64);
            }
            if (l15 == 0) {
                int r = m * 16 + lg * 4 + j;
                s_red[r][w] = s; s_red2[r][w] = s2;
            }
        }
    __syncthreads();
    if (tid < 32) {
        float s  = s_red[tid][0] + s_red[tid][1] + s_red[tid][2] + s_red[tid][3];
        float s2 = s_red2[tid][0] + s_red2[tid][1] + s_red2[tid][2] + s_red2[tid][3];
        float mu = s * (1.f / Hh);
        float var = s2 * (1.f / Hh) - mu * mu;
        s_stats[tid][0] = mu;
        s_stats[tid][1] = rsqrtf(var + 1e-5f);
    }
    __syncthreads();
    #pragma unroll
    for (int n = 0; n < 4; n++) {
        int col = w * 64 + n * 16 + l15;
        gam[n] = gupd[col]; bet[n] = beupd[col];
    }
    float* s_f = (float*)&s_a[0][0];   // reuse as f32, row stride 260
    #pragma unroll
    for (int m = 0; m < 2; m++)
        #pragma unroll
        for (int j = 0; j < 4; j++) {
            int r = m * 16 + lg * 4 + j;
            float mu = s_stats[r][0], rs = s_stats[r][1];
            #pragma unroll
            for (int n = 0; n < 4; n++) {
                float val = (acc[m][n][j] - mu) * rs * gam[n] + bet[n];
                s_f[r * 260 + w * 64 + n * 16 + l15] = val;
            }
        }
    __syncthreads();
    const float4* sf4 = (const float4*)s_f;        // row stride 65 float4
    float4* out4 = (float4*)out + (size_t)n0 * 64;
    #pragma unroll
    for (int i = 0; i < 8; i++) {
        int idx = i * 256 + tid;
        int r = idx >> 6, c4 = idx & 63;
        out4[r * 64 + c4] = sf4[r * 65 + c4];
    }
}

extern "C" void kernel_launch(void* const* d_in, const int* in_sizes, int n_in,
                              void* d_out, int out_size, void* d_ws, size_t ws_size,
                              hipStream_t stream) {
    const float* nf    = (const float*)d_in[0];
    const int* members = (const int*)d_in[1];
    const int* types   = (const int*)d_in[2];
    const void* maskp  = d_in[3];
    const float* ett   = (const float*)d_in[4];
    const float* Wenc  = (const float*)d_in[5];
    const float* benc  = (const float*)d_in[6];
    const float* genc  = (const float*)d_in[7];
    const float* beenc = (const float*)d_in[8];
    const float* Wupd  = (const float*)d_in[9];
    const float* bupd  = (const float*)d_in[10];
    const float* gupd  = (const float*)d_in[11];
    const float* beupd = (const float*)d_in[12];
    float* out = (float*)d_out;

    // workspace layout
    int* ip    = (int*)d_ws;
    int* flag  = ip;                      // 64 ints
    int* deg   = ip + 64;                 // BN
    int* offs  = deg + BN;                // BN+16
    int* cur   = offs + BN + 16;          // BN
    int* iscan = cur + BN;                // BN
    int* bsums = iscan + BN;              // 64
    int* boffs = bsums + 64;              // 64
    int* list  = boffs + 64;              // BE*Aa + 16
    char* p    = (char*)(list + BE * Aa + 16);
    u16* efb   = (u16*)p;   p += (size_t)(BE + 1) * Hh * 2;   // 20.5 MB (+zero row)
    u16* pool  = (u16*)p;   p += (size_t)BE * Hh * 2;         // 20.5 MB (shared w/ updb)
    u16* updb  = pool;                                        // disjoint lifetime
    u16* We1P  = (u16*)p;   p += (size_t)16 * KTE * 64 * 8 * 2;   // 131 KB
    u16* WupdP = (u16*)p;   p += (size_t)16 * KTU * 64 * 8 * 2;   // 262 KB
    float* tb  = (float*)p; p += (size_t)NTy * Hh * 4;            // 16 KB
    u16* nfb   = (u16*)p;   p += (size_t)BN * Hh * 2;             // 20.5 MB (optional)
    const bool use_nfbf = ((size_t)(p - (char*)d_ws) <= ws_size);

    int n4 = (64 + BN) / 4;
    hipLaunchKernelGGL(k_zero, dim3(64), dim3(256), 0, stream, (float4*)ip, n4);
    hipLaunchKernelGGL(k_zero, dim3(1), dim3(64), 0, stream,
                       (float4*)(efb + (size_t)BE * Hh), Hh * 2 / 16);
    hipLaunchKernelGGL(k_detect, dim3(256), dim3(256), 0, stream,
                       (const unsigned int*)maskp, BE * Aa / 4, flag);
    if (use_nfbf)
        hipLaunchKernelGGL(k_cvt, dim3(2048), dim3(256), 0, stream,
                           (const float4*)nf, (ushort4*)nfb, BN * Hh / 4);
    hipLaunchKernelGGL(k_pack, dim3(32), dim3(256), 0, stream,
                       Wenc, We1P, KTE, 16 * KTE * 64);
    hipLaunchKernelGGL(k_pack, dim3(64), dim3(256), 0, stream,
                       Wupd, WupdP, KTU, 16 * KTU * 64);
    hipLaunchKernelGGL(k_prep_tb, dim3(1), dim3(256), 0, stream,
                       ett, Wenc, benc, tb);
    hipLaunchKernelGGL(k_count, dim3(640), dim3(256), 0, stream,
                       members, maskp, flag, deg);
    hipLaunchKernelGGL(k_scan_blk, dim3(NSB), dim3(SCB), 0, stream,
                       deg, iscan, bsums);
    hipLaunchKernelGGL(k_scan_top, dim3(1), dim3(64), 0, stream,
                       bsums, boffs, offs);
    hipLaunchKernelGGL(k_scan_add, dim3((BN + 255) / 256), dim3(256), 0, stream,
                       iscan, deg, boffs, offs, cur);
    hipLaunchKernelGGL(k_fill, dim3(640), dim3(256), 0, stream,
                       members, maskp, flag, cur, list);
    if (use_nfbf)
        hipLaunchKernelGGL((k_gath_edge<true>), dim3(BE * 64 / 512), dim3(512), 0,
                           stream, nf, nfb, members, maskp, flag, pool);
    else
        hipLaunchKernelGGL((k_gath_edge<false>), dim3(BE * 64 / 512), dim3(512), 0,
                           stream, nf, nfb, members, maskp, flag, pool);
    hipLaunchKernelGGL(k_gemm_edge, dim3(BE / 32), dim3(256), 0, stream,
                       pool, types, (const bf16x8*)We1P, tb, genc, beenc,
                       (uint4*)efb);
    hipLaunchKernelGGL(k_gath_node, dim3(BN * 64 / 512), dim3(512), 0, stream,
                       efb, offs, list, updb);
    if (use_nfbf)
        hipLaunchKernelGGL((k_gemm_node<true>), dim3(BN / 32), dim3(256), 0, stream,
                           nf, nfb, updb, (const bf16x8*)WupdP,
                           bupd, gupd, beupd, out);
    else
        hipLaunchKernelGGL((k_gemm_node<false>), dim3(BN / 32), dim3(256), 0, stream,
                           nf, nfb, updb, (const bf16x8*)WupdP,
                           bupd, gupd, beupd, out);
}